// Round 2
// baseline (683.764 us; speedup 1.0000x reference)
//
#include <hip/hip_runtime.h>
#include <math.h>

#define HID 64
#define HEADS 8
#define NUM_LAYERS 3

// ---------------------------------------------------------------------------
// CSR build: counts (atomic), scan+dinv (single block), scatter
// ---------------------------------------------------------------------------
__global__ void k_count(const int* __restrict__ col, int* __restrict__ counts, int E) {
    int e = blockIdx.x * blockDim.x + threadIdx.x;
    if (e < E) atomicAdd(&counts[col[e]], 1);
}

__global__ __launch_bounds__(1024) void k_scan(const int* __restrict__ counts,
                                               int* __restrict__ start,
                                               float* __restrict__ dinv, int n) {
    __shared__ int wsum[16];
    __shared__ int carry_s;
    int tid = threadIdx.x;
    int lane = tid & 63, wv = tid >> 6;
    if (tid == 0) carry_s = 0;
    __syncthreads();
    for (int base = 0; base < n; base += 1024) {
        int i = base + tid;
        int v = (i < n) ? counts[i] : 0;
        int x = v;
#pragma unroll
        for (int off = 1; off < 64; off <<= 1) {
            int y = __shfl_up(x, off);
            if (lane >= off) x += y;
        }
        if (lane == 63) wsum[wv] = x;
        __syncthreads();
        if (wv == 0 && lane < 16) {
            int s = wsum[lane];
#pragma unroll
            for (int off = 1; off < 16; off <<= 1) {
                int y = __shfl_up(s, off);
                if (lane >= off) s += y;
            }
            wsum[lane] = s;
        }
        __syncthreads();
        int waveoff = (wv > 0) ? wsum[wv - 1] : 0;
        int carry = carry_s;
        if (i < n) {
            start[i] = carry + waveoff + x - v;   // exclusive prefix
            dinv[i] = rsqrtf((float)(v + 1));     // +1 self-loop
        }
        __syncthreads();
        if (tid == 0) carry_s = carry + wsum[15];
        __syncthreads();
    }
    if (threadIdx.x == 0) start[n] = carry_s;
}

__global__ void k_scatter(const int* __restrict__ ei, const int* __restrict__ start,
                          int* __restrict__ fill, int* __restrict__ ebuf, int E) {
    int e = blockIdx.x * blockDim.x + threadIdx.x;
    if (e >= E) return;
    int r = ei[e], c = ei[E + e];
    int pos = start[c] + atomicAdd(&fill[c], 1);
    ebuf[pos] = r;
}

// ---------------------------------------------------------------------------
// lin1: h = relu(x @ W1 + b1). 16 nodes/block, 4 oc/thread, float4 weights.
// ---------------------------------------------------------------------------
__global__ __launch_bounds__(256) void k_lin1(const float* __restrict__ x,
                                              const float* __restrict__ w,
                                              const float* __restrict__ b,
                                              float* __restrict__ h, int n) {
    __shared__ float xs[16][257];
    int node0 = blockIdx.x * 16;
    for (int idx = threadIdx.x; idx < 16 * 64; idx += 256) {
        int rrow = idx >> 6, c4 = (idx & 63) * 4;
        int node = node0 + rrow;
        float4 v = (node < n) ? *(const float4*)&x[(size_t)node * 256 + c4]
                              : make_float4(0.f, 0.f, 0.f, 0.f);
        xs[rrow][c4] = v.x; xs[rrow][c4 + 1] = v.y;
        xs[rrow][c4 + 2] = v.z; xs[rrow][c4 + 3] = v.w;
    }
    __syncthreads();
    int ocq = (threadIdx.x & 15) * 4;
    int sub = threadIdx.x >> 4;
    int node = node0 + sub;
    if (node >= n) return;
    float4 acc = make_float4(0.f, 0.f, 0.f, 0.f);
#pragma unroll 8
    for (int c = 0; c < 256; ++c) {
        float xv = xs[sub][c];
        float4 w4 = *(const float4*)&w[c * 64 + ocq];
        acc.x += xv * w4.x; acc.y += xv * w4.y;
        acc.z += xv * w4.z; acc.w += xv * w4.w;
    }
    float4 b4 = *(const float4*)&b[ocq];
    acc.x = fmaxf(acc.x + b4.x, 0.f); acc.y = fmaxf(acc.y + b4.y, 0.f);
    acc.z = fmaxf(acc.z + b4.z, 0.f); acc.w = fmaxf(acc.w + b4.w, 0.f);
    *(float4*)&h[(size_t)node * 64 + ocq] = acc;
}

// ---------------------------------------------------------------------------
// batched 64x64 GEMM for q / K / V of one layer.
// grid.y job: 0 -> q (slice `layer`), 1..t -> K slice s, t+1..2t -> V slice s.
// Slices >= 1 hold raw (pre-relu) sums; relu applied on read.
// ---------------------------------------------------------------------------
__global__ __launch_bounds__(256) void k_qkv(
    const float* __restrict__ xsbase,
    const float* __restrict__ wq, const float* __restrict__ bq,
    const float* __restrict__ wk, const float* __restrict__ bk,
    const float* __restrict__ wv, const float* __restrict__ bv,
    float* __restrict__ q, float* __restrict__ K, float* __restrict__ V,
    int n, int layer, int t) {
    int job = blockIdx.y;
    const float* src; const float* w; const float* b; float* dst; bool relu_in;
    if (job == 0) {
        src = xsbase + (size_t)layer * n * 64;
        w = wq + layer * 4096; b = bq + layer * 64; dst = q;
        relu_in = (layer >= 1);
    } else if (job <= t) {
        int s = job - 1;
        src = xsbase + (size_t)s * n * 64;
        w = wk + layer * 4096; b = bk + layer * 64;
        dst = K + (size_t)s * n * 64;
        relu_in = (s >= 1);
    } else {
        int s = job - t - 1;
        src = xsbase + (size_t)s * n * 64;
        w = wv + layer * 4096; b = bv + layer * 64;
        dst = V + (size_t)s * n * 64;
        relu_in = (s >= 1);
    }
    __shared__ float xl[16][65];
    int node0 = blockIdx.x * 16;
    {
        int rrow = threadIdx.x >> 4, c4 = (threadIdx.x & 15) * 4;
        int node = node0 + rrow;
        float4 v = (node < n) ? *(const float4*)&src[(size_t)node * 64 + c4]
                              : make_float4(0.f, 0.f, 0.f, 0.f);
        if (relu_in) {
            v.x = fmaxf(v.x, 0.f); v.y = fmaxf(v.y, 0.f);
            v.z = fmaxf(v.z, 0.f); v.w = fmaxf(v.w, 0.f);
        }
        xl[rrow][c4] = v.x; xl[rrow][c4 + 1] = v.y;
        xl[rrow][c4 + 2] = v.z; xl[rrow][c4 + 3] = v.w;
    }
    __syncthreads();
    int ocq = (threadIdx.x & 15) * 4;
    int sub = threadIdx.x >> 4;
    int node = node0 + sub;
    if (node >= n) return;
    float4 acc = make_float4(0.f, 0.f, 0.f, 0.f);
#pragma unroll 8
    for (int c = 0; c < 64; ++c) {
        float xv = xl[sub][c];
        float4 w4 = *(const float4*)&w[c * 64 + ocq];
        acc.x += xv * w4.x; acc.y += xv * w4.y;
        acc.z += xv * w4.z; acc.w += xv * w4.w;
    }
    float4 b4 = *(const float4*)&b[ocq];
    acc.x += b4.x; acc.y += b4.y; acc.z += b4.z; acc.w += b4.w;
    *(float4*)&dst[(size_t)node * 64 + ocq] = acc;
}

// ---------------------------------------------------------------------------
// attention + aggregate, CSR by destination. One wave per node; lane = channel.
// Self-loop handled implicitly as iteration j = s0-1.
// ---------------------------------------------------------------------------
__global__ __launch_bounds__(256) void k_attn(
    const int* __restrict__ start, const int* __restrict__ ebuf,
    const float* __restrict__ dinv, const float* __restrict__ q,
    const float* __restrict__ K, const float* __restrict__ V,
    float* __restrict__ outp, int n, int t) {
    int node = (int)((blockIdx.x * (size_t)blockDim.x + threadIdx.x) >> 6);
    int lane = threadIdx.x & 63;
    if (node >= n) return;
    node = __builtin_amdgcn_readfirstlane(node);  // wave-uniform -> scalar loads
    float qv = q[(size_t)node * 64 + lane];
    float dc = dinv[node];
    int s0 = start[node], s1 = start[node + 1];
    const float inv_sqrt_d = 0.35355339059327373f;  // 1/sqrt(8)
    float acc = 0.f;
    int r_next = node;  // first iteration = self-loop
    for (int j = s0 - 1; j < s1; ++j) {
        int r = r_next;
        if (j + 1 < s1) r_next = ebuf[j + 1];
        float dr = dinv[r];
        float sc[NUM_LAYERS];
        float m = -1e30f;
        for (int s = 0; s < t; ++s) {
            float kv = K[((size_t)s * n + r) * 64 + lane];
            float p = qv * kv;
            p += __shfl_xor(p, 1);
            p += __shfl_xor(p, 2);
            p += __shfl_xor(p, 4);
            p *= inv_sqrt_d;
            sc[s] = p;
            m = fmaxf(m, p);
        }
        float denom = 0.f;
        for (int s = 0; s < t; ++s) { sc[s] = __expf(sc[s] - m); denom += sc[s]; }
        float wgt = dr / denom;
        float msg = 0.f;
        for (int s = 0; s < t; ++s) {
            msg += sc[s] * V[((size_t)s * n + r) * 64 + lane];
        }
        acc += msg * wgt;
    }
    outp[(size_t)node * 64 + lane] = acc * dc;
}

// ---------------------------------------------------------------------------
// final: logits = relu(x3) @ W2 + b2 -> log_softmax. One wave per node.
// ---------------------------------------------------------------------------
__global__ __launch_bounds__(256) void k_final(
    const float* __restrict__ x3, const float* __restrict__ w,
    const float* __restrict__ b, float* __restrict__ outp, int n) {
    int wid  = (int)((blockIdx.x * (size_t)blockDim.x + threadIdx.x) >> 6);
    int lane = threadIdx.x & 63;
    if (wid >= n) return;
    float xv = fmaxf(x3[(size_t)wid * 64 + lane], 0.f);
    float acc = b[lane];
#pragma unroll
    for (int c = 0; c < 64; ++c) {
        float xc = __shfl(xv, c);
        acc += xc * w[c * 64 + lane];
    }
    float m = acc;
    for (int off = 1; off < 64; off <<= 1) m = fmaxf(m, __shfl_xor(m, off));
    float e = __expf(acc - m);
    float ssum = e;
    for (int off = 1; off < 64; off <<= 1) ssum += __shfl_xor(ssum, off);
    outp[(size_t)wid * 64 + lane] = acc - m - __logf(ssum);
}

// ---------------------------------------------------------------------------
extern "C" void kernel_launch(void* const* d_in, const int* in_sizes, int n_in,
                              void* d_out, int out_size, void* d_ws, size_t ws_size,
                              hipStream_t stream) {
    const float* x  = (const float*)d_in[0];
    const int*   ei = (const int*)d_in[1];
    const float* w1 = (const float*)d_in[2];
    const float* b1 = (const float*)d_in[3];
    const float* wq = (const float*)d_in[4];
    const float* bq = (const float*)d_in[5];
    const float* wk = (const float*)d_in[6];
    const float* bk = (const float*)d_in[7];
    const float* wv = (const float*)d_in[8];
    const float* bv = (const float*)d_in[9];
    const float* w2 = (const float*)d_in[10];
    const float* b2 = (const float*)d_in[11];
    float* outp = (float*)d_out;

    int n = in_sizes[0] / 256;
    int E = in_sizes[1] / 2;

    float* ws = (float*)d_ws;
    size_t off = 0;
    float* dinv = ws + off; off += (size_t)n;
    float* q    = ws + off; off += (size_t)n * 64;
    float* K    = ws + off; off += (size_t)n * 64 * NUM_LAYERS;
    float* V    = ws + off; off += (size_t)n * 64 * NUM_LAYERS;
    float* xs   = ws + off; off += (size_t)n * 64 * (NUM_LAYERS + 1);
    int* wsI    = (int*)(ws + off);
    int* counts = wsI;                 // n
    int* fill   = wsI + n;             // n
    int* startA = wsI + 2 * n;         // n+1
    int* ebuf   = wsI + 3 * n + 1;     // E

    // CSR build (counts+fill zeroed in one memset)
    hipMemsetAsync(counts, 0, 2 * (size_t)n * sizeof(int), stream);
    k_count<<<(E + 255) / 256, 256, 0, stream>>>(ei + E, counts, E);
    k_scan<<<1, 1024, 0, stream>>>(counts, startA, dinv, n);
    k_scatter<<<(E + 255) / 256, 256, 0, stream>>>(ei, startA, fill, ebuf, E);

    k_lin1<<<(n + 15) / 16, 256, 0, stream>>>(x, w1, b1, xs, n);

    for (int l = 0; l < NUM_LAYERS; ++l) {
        int t = l + 1;
        dim3 grid((n + 15) / 16, 1 + 2 * t);
        k_qkv<<<grid, 256, 0, stream>>>(xs, wq, bq, wk, bk, wv, bv,
                                        q, K, V, n, l, t);
        float* dst = xs + (size_t)(l + 1) * n * 64;
        k_attn<<<(int)(((size_t)n * 64 + 255) / 256), 256, 0, stream>>>(
            startA, ebuf, dinv, q, K, V, dst, n, t);
    }

    k_final<<<((int)(((long long)n * 64 + 255) / 256)), 256, 0, stream>>>(
        xs + (size_t)NUM_LAYERS * n * 64, w2, b2, outp, n);
}

// Round 3
// 455.561 us; speedup vs baseline: 1.5009x; 1.5009x over previous
//
#include <hip/hip_runtime.h>
#include <math.h>

#define HID 64
#define HEADS 8
#define NUM_LAYERS 3

// ---------------------------------------------------------------------------
// CSR build: counts (atomic), scan+dinv (single block), scatter
// ---------------------------------------------------------------------------
__global__ void k_count(const int* __restrict__ col, int* __restrict__ counts, int E) {
    int e = blockIdx.x * blockDim.x + threadIdx.x;
    if (e < E) atomicAdd(&counts[col[e]], 1);
}

__global__ __launch_bounds__(1024) void k_scan(const int* __restrict__ counts,
                                               int* __restrict__ start,
                                               float* __restrict__ dinv, int n) {
    __shared__ int wsum[16];
    __shared__ int carry_s;
    int tid = threadIdx.x;
    int lane = tid & 63, wv = tid >> 6;
    if (tid == 0) carry_s = 0;
    __syncthreads();
    for (int base = 0; base < n; base += 1024) {
        int i = base + tid;
        int v = (i < n) ? counts[i] : 0;
        int x = v;
#pragma unroll
        for (int off = 1; off < 64; off <<= 1) {
            int y = __shfl_up(x, off);
            if (lane >= off) x += y;
        }
        if (lane == 63) wsum[wv] = x;
        __syncthreads();
        if (wv == 0 && lane < 16) {
            int s = wsum[lane];
#pragma unroll
            for (int off = 1; off < 16; off <<= 1) {
                int y = __shfl_up(s, off);
                if (lane >= off) s += y;
            }
            wsum[lane] = s;
        }
        __syncthreads();
        int waveoff = (wv > 0) ? wsum[wv - 1] : 0;
        int carry = carry_s;
        if (i < n) {
            start[i] = carry + waveoff + x - v;   // exclusive prefix
            dinv[i] = rsqrtf((float)(v + 1));     // +1 self-loop
        }
        __syncthreads();
        if (tid == 0) carry_s = carry + wsum[15];
        __syncthreads();
    }
    if (threadIdx.x == 0) start[n] = carry_s;
}

__global__ void k_scatter(const int* __restrict__ ei, const int* __restrict__ start,
                          int* __restrict__ fill, int* __restrict__ ebuf, int E) {
    int e = blockIdx.x * blockDim.x + threadIdx.x;
    if (e >= E) return;
    int r = ei[e], c = ei[E + e];
    int pos = start[c] + atomicAdd(&fill[c], 1);
    ebuf[pos] = r;
}

// ---------------------------------------------------------------------------
// lin1: h = relu(x @ W1 + b1). 16 nodes/block, 4 oc/thread, float4 weights.
// ---------------------------------------------------------------------------
__global__ __launch_bounds__(256) void k_lin1(const float* __restrict__ x,
                                              const float* __restrict__ w,
                                              const float* __restrict__ b,
                                              float* __restrict__ h, int n) {
    __shared__ float xs[16][257];
    int node0 = blockIdx.x * 16;
    for (int idx = threadIdx.x; idx < 16 * 64; idx += 256) {
        int rrow = idx >> 6, c4 = (idx & 63) * 4;
        int node = node0 + rrow;
        float4 v = (node < n) ? *(const float4*)&x[(size_t)node * 256 + c4]
                              : make_float4(0.f, 0.f, 0.f, 0.f);
        xs[rrow][c4] = v.x; xs[rrow][c4 + 1] = v.y;
        xs[rrow][c4 + 2] = v.z; xs[rrow][c4 + 3] = v.w;
    }
    __syncthreads();
    int ocq = (threadIdx.x & 15) * 4;
    int sub = threadIdx.x >> 4;
    int node = node0 + sub;
    if (node >= n) return;
    float4 acc = make_float4(0.f, 0.f, 0.f, 0.f);
#pragma unroll 8
    for (int c = 0; c < 256; ++c) {
        float xv = xs[sub][c];
        float4 w4 = *(const float4*)&w[c * 64 + ocq];
        acc.x += xv * w4.x; acc.y += xv * w4.y;
        acc.z += xv * w4.z; acc.w += xv * w4.w;
    }
    float4 b4 = *(const float4*)&b[ocq];
    acc.x = fmaxf(acc.x + b4.x, 0.f); acc.y = fmaxf(acc.y + b4.y, 0.f);
    acc.z = fmaxf(acc.z + b4.z, 0.f); acc.w = fmaxf(acc.w + b4.w, 0.f);
    *(float4*)&h[(size_t)node * 64 + ocq] = acc;
}

// ---------------------------------------------------------------------------
// batched 64x64 GEMM for q / K / V of one layer.
// job (blockIdx.y + job_offset): 0 -> q (slice `layer`), 1..t -> K slice s,
// t+1..2t -> V slice s.  Slices >= 1 hold raw sums; relu applied on read.
// For layer 0 only the V job is launched (job_offset = 2): t=1 softmax == 1,
// so q and K are dead.
// ---------------------------------------------------------------------------
__global__ __launch_bounds__(256) void k_qkv(
    const float* __restrict__ xsbase,
    const float* __restrict__ wq, const float* __restrict__ bq,
    const float* __restrict__ wk, const float* __restrict__ bk,
    const float* __restrict__ wv, const float* __restrict__ bv,
    float* __restrict__ q, float* __restrict__ K, float* __restrict__ V,
    int n, int layer, int t, int job_offset) {
    int job = blockIdx.y + job_offset;
    const float* src; const float* w; const float* b; float* dst; bool relu_in;
    if (job == 0) {
        src = xsbase + (size_t)layer * n * 64;
        w = wq + layer * 4096; b = bq + layer * 64; dst = q;
        relu_in = (layer >= 1);
    } else if (job <= t) {
        int s = job - 1;
        src = xsbase + (size_t)s * n * 64;
        w = wk + layer * 4096; b = bk + layer * 64;
        dst = K + (size_t)s * n * 64;
        relu_in = (s >= 1);
    } else {
        int s = job - t - 1;
        src = xsbase + (size_t)s * n * 64;
        w = wv + layer * 4096; b = bv + layer * 64;
        dst = V + (size_t)s * n * 64;
        relu_in = (s >= 1);
    }
    __shared__ float xl[16][65];
    int node0 = blockIdx.x * 16;
    {
        int rrow = threadIdx.x >> 4, c4 = (threadIdx.x & 15) * 4;
        int node = node0 + rrow;
        float4 v = (node < n) ? *(const float4*)&src[(size_t)node * 64 + c4]
                              : make_float4(0.f, 0.f, 0.f, 0.f);
        if (relu_in) {
            v.x = fmaxf(v.x, 0.f); v.y = fmaxf(v.y, 0.f);
            v.z = fmaxf(v.z, 0.f); v.w = fmaxf(v.w, 0.f);
        }
        xl[rrow][c4] = v.x; xl[rrow][c4 + 1] = v.y;
        xl[rrow][c4 + 2] = v.z; xl[rrow][c4 + 3] = v.w;
    }
    __syncthreads();
    int ocq = (threadIdx.x & 15) * 4;
    int sub = threadIdx.x >> 4;
    int node = node0 + sub;
    if (node >= n) return;
    float4 acc = make_float4(0.f, 0.f, 0.f, 0.f);
#pragma unroll 8
    for (int c = 0; c < 64; ++c) {
        float xv = xl[sub][c];
        float4 w4 = *(const float4*)&w[c * 64 + ocq];
        acc.x += xv * w4.x; acc.y += xv * w4.y;
        acc.z += xv * w4.z; acc.w += xv * w4.w;
    }
    float4 b4 = *(const float4*)&b[ocq];
    acc.x += b4.x; acc.y += b4.y; acc.z += b4.z; acc.w += b4.w;
    *(float4*)&dst[(size_t)node * 64 + ocq] = acc;
}

// ---------------------------------------------------------------------------
// attention + aggregate, CSR by destination.  One wave per node.
// Lane = (edge-slot g = lane>>3, head h = lane&7): 8 edges in flight,
// each lane owns one head's d=8 slice -> dot products and softmax are
// lane-local (NO per-edge shuffles).  Cross-slot reduction once per node.
// T==1: softmax over one element == 1 -> pure dinv-weighted V gather.
// ---------------------------------------------------------------------------
template <int T>
__global__ __launch_bounds__(256) void k_attn_g(
    const int* __restrict__ start, const int* __restrict__ ebuf,
    const float* __restrict__ dinv, const float* __restrict__ q,
    const float* __restrict__ K, const float* __restrict__ V,
    float* __restrict__ outp, int n) {
    int node = (int)((blockIdx.x * (size_t)blockDim.x + threadIdx.x) >> 6);
    int lane = threadIdx.x & 63;
    if (node >= n) return;
    int g = lane >> 3;        // edge slot 0..7
    int cb = (lane & 7) * 8;  // channel base for this head
    const float isd = 0.35355339059327373f;  // 1/sqrt(8)

    float qv[8];
    if (T > 1) {
        float4 q0 = *(const float4*)&q[(size_t)node * 64 + cb];
        float4 q1 = *(const float4*)&q[(size_t)node * 64 + cb + 4];
        qv[0] = q0.x; qv[1] = q0.y; qv[2] = q0.z; qv[3] = q0.w;
        qv[4] = q1.x; qv[5] = q1.y; qv[6] = q1.z; qv[7] = q1.w;
    }
    float dc = dinv[node];
    int s0 = start[node];
    int cnt = start[node + 1] - s0 + 1;  // + self-loop (item 0)

    float acc[8];
#pragma unroll
    for (int k = 0; k < 8; ++k) acc[k] = 0.f;

    for (int base = 0; base < cnt; base += 8) {
        int idx = base + g;
        bool valid = idx < cnt;
        int r = node;                      // item 0 = self-loop
        if (valid && idx > 0) r = ebuf[s0 + idx - 1];
        float dr = valid ? dinv[r] : 0.f;  // invalid slots contribute 0

        float sc[T];
        float wgt;
        if (T > 1) {
            float m = -1e30f;
#pragma unroll
            for (int s = 0; s < T; ++s) {
                const float* kr = &K[((size_t)s * n + r) * 64 + cb];
                float4 k0 = *(const float4*)kr;
                float4 k1 = *(const float4*)(kr + 4);
                float p = qv[0] * k0.x + qv[1] * k0.y + qv[2] * k0.z + qv[3] * k0.w
                        + qv[4] * k1.x + qv[5] * k1.y + qv[6] * k1.z + qv[7] * k1.w;
                p *= isd;
                sc[s] = p;
                m = fmaxf(m, p);
            }
            float denom = 0.f;
#pragma unroll
            for (int s = 0; s < T; ++s) { sc[s] = __expf(sc[s] - m); denom += sc[s]; }
            wgt = dr / denom;
        } else {
            sc[0] = 1.f;
            wgt = dr;
        }

        float mg[8];
#pragma unroll
        for (int k = 0; k < 8; ++k) mg[k] = 0.f;
#pragma unroll
        for (int s = 0; s < T; ++s) {
            const float* vr = &V[((size_t)s * n + r) * 64 + cb];
            float4 v0 = *(const float4*)vr;
            float4 v1 = *(const float4*)(vr + 4);
            float wv_ = sc[s];
            mg[0] += wv_ * v0.x; mg[1] += wv_ * v0.y;
            mg[2] += wv_ * v0.z; mg[3] += wv_ * v0.w;
            mg[4] += wv_ * v1.x; mg[5] += wv_ * v1.y;
            mg[6] += wv_ * v1.z; mg[7] += wv_ * v1.w;
        }
#pragma unroll
        for (int k = 0; k < 8; ++k) acc[k] += wgt * mg[k];
    }

    // reduce the 8 edge slots (lanes stride-8 apart hold the same head)
#pragma unroll
    for (int off = 8; off < 64; off <<= 1) {
#pragma unroll
        for (int k = 0; k < 8; ++k) acc[k] += __shfl_xor(acc[k], off);
    }
    if (g == 0) {
        float4 o0 = make_float4(acc[0] * dc, acc[1] * dc, acc[2] * dc, acc[3] * dc);
        float4 o1 = make_float4(acc[4] * dc, acc[5] * dc, acc[6] * dc, acc[7] * dc);
        *(float4*)&outp[(size_t)node * 64 + cb] = o0;
        *(float4*)&outp[(size_t)node * 64 + cb + 4] = o1;
    }
}

// ---------------------------------------------------------------------------
// final: logits = relu(x3) @ W2 + b2 -> log_softmax. One wave per node.
// ---------------------------------------------------------------------------
__global__ __launch_bounds__(256) void k_final(
    const float* __restrict__ x3, const float* __restrict__ w,
    const float* __restrict__ b, float* __restrict__ outp, int n) {
    int wid  = (int)((blockIdx.x * (size_t)blockDim.x + threadIdx.x) >> 6);
    int lane = threadIdx.x & 63;
    if (wid >= n) return;
    float xv = fmaxf(x3[(size_t)wid * 64 + lane], 0.f);
    float acc = b[lane];
#pragma unroll
    for (int c = 0; c < 64; ++c) {
        float xc = __shfl(xv, c);
        acc += xc * w[c * 64 + lane];
    }
    float m = acc;
    for (int off = 1; off < 64; off <<= 1) m = fmaxf(m, __shfl_xor(m, off));
    float e = __expf(acc - m);
    float ssum = e;
    for (int off = 1; off < 64; off <<= 1) ssum += __shfl_xor(ssum, off);
    outp[(size_t)wid * 64 + lane] = acc - m - __logf(ssum);
}

// ---------------------------------------------------------------------------
extern "C" void kernel_launch(void* const* d_in, const int* in_sizes, int n_in,
                              void* d_out, int out_size, void* d_ws, size_t ws_size,
                              hipStream_t stream) {
    const float* x  = (const float*)d_in[0];
    const int*   ei = (const int*)d_in[1];
    const float* w1 = (const float*)d_in[2];
    const float* b1 = (const float*)d_in[3];
    const float* wq = (const float*)d_in[4];
    const float* bq = (const float*)d_in[5];
    const float* wk = (const float*)d_in[6];
    const float* bk = (const float*)d_in[7];
    const float* wv = (const float*)d_in[8];
    const float* bv = (const float*)d_in[9];
    const float* w2 = (const float*)d_in[10];
    const float* b2 = (const float*)d_in[11];
    float* outp = (float*)d_out;

    int n = in_sizes[0] / 256;
    int E = in_sizes[1] / 2;

    float* ws = (float*)d_ws;
    size_t off = 0;
    float* dinv = ws + off; off += (size_t)n;
    float* q    = ws + off; off += (size_t)n * 64;
    float* K    = ws + off; off += (size_t)n * 64 * NUM_LAYERS;
    float* V    = ws + off; off += (size_t)n * 64 * NUM_LAYERS;
    float* xs   = ws + off; off += (size_t)n * 64 * (NUM_LAYERS + 1);
    int* wsI    = (int*)(ws + off);
    int* counts = wsI;                 // n
    int* fill   = wsI + n;             // n
    int* startA = wsI + 2 * n;         // n+1
    int* ebuf   = wsI + 3 * n + 1;     // E

    // CSR build (counts+fill zeroed in one memset)
    hipMemsetAsync(counts, 0, 2 * (size_t)n * sizeof(int), stream);
    k_count<<<(E + 255) / 256, 256, 0, stream>>>(ei + E, counts, E);
    k_scan<<<1, 1024, 0, stream>>>(counts, startA, dinv, n);
    k_scatter<<<(E + 255) / 256, 256, 0, stream>>>(ei, startA, fill, ebuf, E);

    k_lin1<<<(n + 15) / 16, 256, 0, stream>>>(x, w1, b1, xs, n);

    int attn_grid = (int)(((size_t)n * 64 + 255) / 256);
    for (int l = 0; l < NUM_LAYERS; ++l) {
        int t = l + 1;
        // layer 0: only V needed (softmax over 1 element == 1)
        int job_offset = (l == 0) ? 2 : 0;
        int njobs      = (l == 0) ? 1 : 1 + 2 * t;
        dim3 grid((n + 15) / 16, njobs);
        k_qkv<<<grid, 256, 0, stream>>>(xs, wq, bq, wk, bk, wv, bv,
                                        q, K, V, n, l, t, job_offset);
        float* dst = xs + (size_t)(l + 1) * n * 64;
        if (t == 1)
            k_attn_g<1><<<attn_grid, 256, 0, stream>>>(startA, ebuf, dinv, q, K, V, dst, n);
        else if (t == 2)
            k_attn_g<2><<<attn_grid, 256, 0, stream>>>(startA, ebuf, dinv, q, K, V, dst, n);
        else
            k_attn_g<3><<<attn_grid, 256, 0, stream>>>(startA, ebuf, dinv, q, K, V, dst, n);
    }

    k_final<<<((int)(((long long)n * 64 + 255) / 256)), 256, 0, stream>>>(
        xs + (size_t)NUM_LAYERS * n * 64, w2, b2, outp, n);
}

// Round 4
// 356.442 us; speedup vs baseline: 1.9183x; 1.2781x over previous
//
#include <hip/hip_runtime.h>
#include <math.h>

#define HID 64
#define HEADS 8
#define NUM_LAYERS 3

// ---------------------------------------------------------------------------
// CSR build: counts (atomic), scan+dinv (single block), scatter
// ---------------------------------------------------------------------------
__global__ void k_count(const int* __restrict__ col, int* __restrict__ counts, int E) {
    int e = blockIdx.x * blockDim.x + threadIdx.x;
    if (e < E) atomicAdd(&counts[col[e]], 1);
}

__global__ __launch_bounds__(1024) void k_scan(const int* __restrict__ counts,
                                               int* __restrict__ start,
                                               float* __restrict__ dinv, int n) {
    __shared__ int wsum[16];
    __shared__ int carry_s;
    int tid = threadIdx.x;
    int lane = tid & 63, wv = tid >> 6;
    if (tid == 0) carry_s = 0;
    __syncthreads();
    for (int base = 0; base < n; base += 1024) {
        int i = base + tid;
        int v = (i < n) ? counts[i] : 0;
        int x = v;
#pragma unroll
        for (int off = 1; off < 64; off <<= 1) {
            int y = __shfl_up(x, off);
            if (lane >= off) x += y;
        }
        if (lane == 63) wsum[wv] = x;
        __syncthreads();
        if (wv == 0 && lane < 16) {
            int s = wsum[lane];
#pragma unroll
            for (int off = 1; off < 16; off <<= 1) {
                int y = __shfl_up(s, off);
                if (lane >= off) s += y;
            }
            wsum[lane] = s;
        }
        __syncthreads();
        int waveoff = (wv > 0) ? wsum[wv - 1] : 0;
        int carry = carry_s;
        if (i < n) {
            start[i] = carry + waveoff + x - v;   // exclusive prefix
            dinv[i] = rsqrtf((float)(v + 1));     // +1 self-loop
        }
        __syncthreads();
        if (tid == 0) carry_s = carry + wsum[15];
        __syncthreads();
    }
    if (threadIdx.x == 0) start[n] = carry_s;
}

__global__ void k_scatter(const int* __restrict__ ei, const int* __restrict__ start,
                          int* __restrict__ fill, int* __restrict__ ebuf, int E) {
    int e = blockIdx.x * blockDim.x + threadIdx.x;
    if (e >= E) return;
    int r = ei[e], c = ei[E + e];
    int pos = start[c] + atomicAdd(&fill[c], 1);
    ebuf[pos] = r;
}

// ---------------------------------------------------------------------------
// Register-tiled GEMM building block:
//   64-node x 64-oc tile, 256 threads, 4x4 acc per thread.
//   W (64x64) in LDS; src tile transposed in LDS (stride 68 -> 16B aligned,
//   banks spread).  Inner iter: 2x ds_read_b128 + 16 FMA, no global loads.
// ---------------------------------------------------------------------------
#define ST_STRIDE 68

__device__ __forceinline__ void gemm_tile_stage_src(
    float* st, const float* __restrict__ src, int node0, int n, int ld,
    int kc, bool relu_in, int tid) {
    int nd = tid >> 4;             // 0..15
    int c4 = (tid & 15) * 4;       // 0..60
#pragma unroll
    for (int rep = 0; rep < 4; ++rep) {
        int lnode = nd + rep * 16;
        int node = node0 + lnode;
        float4 v = make_float4(0.f, 0.f, 0.f, 0.f);
        if (node < n) v = *(const float4*)&src[(size_t)node * ld + kc + c4];
        if (relu_in) {
            v.x = fmaxf(v.x, 0.f); v.y = fmaxf(v.y, 0.f);
            v.z = fmaxf(v.z, 0.f); v.w = fmaxf(v.w, 0.f);
        }
        st[(c4 + 0) * ST_STRIDE + lnode] = v.x;
        st[(c4 + 1) * ST_STRIDE + lnode] = v.y;
        st[(c4 + 2) * ST_STRIDE + lnode] = v.z;
        st[(c4 + 3) * ST_STRIDE + lnode] = v.w;
    }
}

__device__ __forceinline__ void gemm_tile_inner(
    const float* st, const float* wl, int ri, int j, float acc[4][4]) {
#pragma unroll 4
    for (int c = 0; c < 64; ++c) {
        float4 a  = *(const float4*)&st[c * ST_STRIDE + ri * 4];
        float4 b4 = *(const float4*)&wl[c * 64 + j * 4];
        acc[0][0] += a.x * b4.x; acc[0][1] += a.x * b4.y;
        acc[0][2] += a.x * b4.z; acc[0][3] += a.x * b4.w;
        acc[1][0] += a.y * b4.x; acc[1][1] += a.y * b4.y;
        acc[1][2] += a.y * b4.z; acc[1][3] += a.y * b4.w;
        acc[2][0] += a.z * b4.x; acc[2][1] += a.z * b4.y;
        acc[2][2] += a.z * b4.z; acc[2][3] += a.z * b4.w;
        acc[3][0] += a.w * b4.x; acc[3][1] += a.w * b4.y;
        acc[3][2] += a.w * b4.z; acc[3][3] += a.w * b4.w;
    }
}

// ---------------------------------------------------------------------------
// lin1: h = relu(x @ W1 + b1), K = 256 chunked by 64.
// ---------------------------------------------------------------------------
__global__ __launch_bounds__(256, 4) void k_lin1(const float* __restrict__ x,
                                                 const float* __restrict__ w,
                                                 const float* __restrict__ b,
                                                 float* __restrict__ h, int n) {
    __shared__ float wl[64 * 64];
    __shared__ float st[64 * ST_STRIDE];
    int tid = threadIdx.x;
    int node0 = blockIdx.x * 64;
    int ri = tid >> 4, j = tid & 15;
    float acc[4][4];
#pragma unroll
    for (int m = 0; m < 4; ++m)
#pragma unroll
        for (int k = 0; k < 4; ++k) acc[m][k] = 0.f;

    for (int kc = 0; kc < 256; kc += 64) {
        for (int i = tid * 4; i < 4096; i += 1024)
            *(float4*)&wl[i] = *(const float4*)&w[kc * 64 + i];
        gemm_tile_stage_src(st, x, node0, n, 256, kc, false, tid);
        __syncthreads();
        gemm_tile_inner(st, wl, ri, j, acc);
        __syncthreads();
    }
    float4 bb = *(const float4*)&b[j * 4];
#pragma unroll
    for (int m = 0; m < 4; ++m) {
        int node = node0 + ri * 4 + m;
        if (node < n) {
            float4 o = make_float4(fmaxf(acc[m][0] + bb.x, 0.f),
                                   fmaxf(acc[m][1] + bb.y, 0.f),
                                   fmaxf(acc[m][2] + bb.z, 0.f),
                                   fmaxf(acc[m][3] + bb.w, 0.f));
            *(float4*)&h[(size_t)node * 64 + j * 4] = o;
        }
    }
}

// ---------------------------------------------------------------------------
// batched 64x64 GEMM for q / K / V of one layer (register-tiled).
// job (blockIdx.y + job_offset): 0 -> q (slice `layer`), 1..t -> K slice s,
// t+1..2t -> V slice s.  Slices >= 1 hold raw sums; relu applied on read.
// Layer 0 launches only the V job (job_offset = 2).
// ---------------------------------------------------------------------------
__global__ __launch_bounds__(256, 4) void k_qkv(
    const float* __restrict__ xsbase,
    const float* __restrict__ wq, const float* __restrict__ bq,
    const float* __restrict__ wk, const float* __restrict__ bk,
    const float* __restrict__ wv, const float* __restrict__ bv,
    float* __restrict__ q, float* __restrict__ K, float* __restrict__ V,
    int n, int layer, int t, int job_offset) {
    int job = blockIdx.y + job_offset;
    const float* src; const float* w; const float* b; float* dst; bool relu_in;
    if (job == 0) {
        src = xsbase + (size_t)layer * n * 64;
        w = wq + layer * 4096; b = bq + layer * 64; dst = q;
        relu_in = (layer >= 1);
    } else if (job <= t) {
        int s = job - 1;
        src = xsbase + (size_t)s * n * 64;
        w = wk + layer * 4096; b = bk + layer * 64;
        dst = K + (size_t)s * n * 64;
        relu_in = (s >= 1);
    } else {
        int s = job - t - 1;
        src = xsbase + (size_t)s * n * 64;
        w = wv + layer * 4096; b = bv + layer * 64;
        dst = V + (size_t)s * n * 64;
        relu_in = (s >= 1);
    }
    __shared__ float wl[64 * 64];
    __shared__ float st[64 * ST_STRIDE];
    int tid = threadIdx.x;
    int node0 = blockIdx.x * 64;
    for (int i = tid * 4; i < 4096; i += 1024)
        *(float4*)&wl[i] = *(const float4*)&w[i];
    gemm_tile_stage_src(st, src, node0, n, 64, 0, relu_in, tid);
    __syncthreads();
    int ri = tid >> 4, j = tid & 15;
    float acc[4][4];
#pragma unroll
    for (int m = 0; m < 4; ++m)
#pragma unroll
        for (int k = 0; k < 4; ++k) acc[m][k] = 0.f;
    gemm_tile_inner(st, wl, ri, j, acc);
    float4 bb = *(const float4*)&b[j * 4];
#pragma unroll
    for (int m = 0; m < 4; ++m) {
        int node = node0 + ri * 4 + m;
        if (node < n) {
            float4 o = make_float4(acc[m][0] + bb.x, acc[m][1] + bb.y,
                                   acc[m][2] + bb.z, acc[m][3] + bb.w);
            *(float4*)&dst[(size_t)node * 64 + j * 4] = o;
        }
    }
}

// ---------------------------------------------------------------------------
// attention + aggregate, CSR by destination.  One wave per node.
// Lane = (edge-slot g = lane>>3, head h = lane&7): 8 edges in flight,
// lane-local dot/softmax; cross-slot reduction once per node.
// T==1: softmax == 1 -> pure dinv-weighted V gather.
// ---------------------------------------------------------------------------
template <int T>
__global__ __launch_bounds__(256) void k_attn_g(
    const int* __restrict__ start, const int* __restrict__ ebuf,
    const float* __restrict__ dinv, const float* __restrict__ q,
    const float* __restrict__ K, const float* __restrict__ V,
    float* __restrict__ outp, int n) {
    int node = (int)((blockIdx.x * (size_t)blockDim.x + threadIdx.x) >> 6);
    int lane = threadIdx.x & 63;
    if (node >= n) return;
    int g = lane >> 3;        // edge slot 0..7
    int cb = (lane & 7) * 8;  // channel base for this head
    const float isd = 0.35355339059327373f;  // 1/sqrt(8)

    float qv[8];
    if (T > 1) {
        float4 q0 = *(const float4*)&q[(size_t)node * 64 + cb];
        float4 q1 = *(const float4*)&q[(size_t)node * 64 + cb + 4];
        qv[0] = q0.x; qv[1] = q0.y; qv[2] = q0.z; qv[3] = q0.w;
        qv[4] = q1.x; qv[5] = q1.y; qv[6] = q1.z; qv[7] = q1.w;
    }
    float dc = dinv[node];
    int s0 = start[node];
    int cnt = start[node + 1] - s0 + 1;  // + self-loop (item 0)

    float acc[8];
#pragma unroll
    for (int k = 0; k < 8; ++k) acc[k] = 0.f;

    for (int base = 0; base < cnt; base += 8) {
        int idx = base + g;
        bool valid = idx < cnt;
        int r = node;                      // item 0 = self-loop
        if (valid && idx > 0) r = ebuf[s0 + idx - 1];
        float dr = valid ? dinv[r] : 0.f;  // invalid slots contribute 0

        float sc[T];
        float wgt;
        if (T > 1) {
            float m = -1e30f;
#pragma unroll
            for (int s = 0; s < T; ++s) {
                const float* kr = &K[((size_t)s * n + r) * 64 + cb];
                float4 k0 = *(const float4*)kr;
                float4 k1 = *(const float4*)(kr + 4);
                float p = qv[0] * k0.x + qv[1] * k0.y + qv[2] * k0.z + qv[3] * k0.w
                        + qv[4] * k1.x + qv[5] * k1.y + qv[6] * k1.z + qv[7] * k1.w;
                p *= isd;
                sc[s] = p;
                m = fmaxf(m, p);
            }
            float denom = 0.f;
#pragma unroll
            for (int s = 0; s < T; ++s) { sc[s] = __expf(sc[s] - m); denom += sc[s]; }
            wgt = dr / denom;
        } else {
            sc[0] = 1.f;
            wgt = dr;
        }

        float mg[8];
#pragma unroll
        for (int k = 0; k < 8; ++k) mg[k] = 0.f;
#pragma unroll
        for (int s = 0; s < T; ++s) {
            const float* vr = &V[((size_t)s * n + r) * 64 + cb];
            float4 v0 = *(const float4*)vr;
            float4 v1 = *(const float4*)(vr + 4);
            float wv_ = sc[s];
            mg[0] += wv_ * v0.x; mg[1] += wv_ * v0.y;
            mg[2] += wv_ * v0.z; mg[3] += wv_ * v0.w;
            mg[4] += wv_ * v1.x; mg[5] += wv_ * v1.y;
            mg[6] += wv_ * v1.z; mg[7] += wv_ * v1.w;
        }
#pragma unroll
        for (int k = 0; k < 8; ++k) acc[k] += wgt * mg[k];
    }

#pragma unroll
    for (int off = 8; off < 64; off <<= 1) {
#pragma unroll
        for (int k = 0; k < 8; ++k) acc[k] += __shfl_xor(acc[k], off);
    }
    if (g == 0) {
        float4 o0 = make_float4(acc[0] * dc, acc[1] * dc, acc[2] * dc, acc[3] * dc);
        float4 o1 = make_float4(acc[4] * dc, acc[5] * dc, acc[6] * dc, acc[7] * dc);
        *(float4*)&outp[(size_t)node * 64 + cb] = o0;
        *(float4*)&outp[(size_t)node * 64 + cb + 4] = o1;
    }
}

// ---------------------------------------------------------------------------
// final: logits = relu(x3) @ W2 + b2 -> log_softmax. One wave per node.
// ---------------------------------------------------------------------------
__global__ __launch_bounds__(256) void k_final(
    const float* __restrict__ x3, const float* __restrict__ w,
    const float* __restrict__ b, float* __restrict__ outp, int n) {
    int wid  = (int)((blockIdx.x * (size_t)blockDim.x + threadIdx.x) >> 6);
    int lane = threadIdx.x & 63;
    if (wid >= n) return;
    float xv = fmaxf(x3[(size_t)wid * 64 + lane], 0.f);
    float acc = b[lane];
#pragma unroll
    for (int c = 0; c < 64; ++c) {
        float xc = __shfl(xv, c);
        acc += xc * w[c * 64 + lane];
    }
    float m = acc;
    for (int off = 1; off < 64; off <<= 1) m = fmaxf(m, __shfl_xor(m, off));
    float e = __expf(acc - m);
    float ssum = e;
    for (int off = 1; off < 64; off <<= 1) ssum += __shfl_xor(ssum, off);
    outp[(size_t)wid * 64 + lane] = acc - m - __logf(ssum);
}

// ---------------------------------------------------------------------------
extern "C" void kernel_launch(void* const* d_in, const int* in_sizes, int n_in,
                              void* d_out, int out_size, void* d_ws, size_t ws_size,
                              hipStream_t stream) {
    const float* x  = (const float*)d_in[0];
    const int*   ei = (const int*)d_in[1];
    const float* w1 = (const float*)d_in[2];
    const float* b1 = (const float*)d_in[3];
    const float* wq = (const float*)d_in[4];
    const float* bq = (const float*)d_in[5];
    const float* wk = (const float*)d_in[6];
    const float* bk = (const float*)d_in[7];
    const float* wv = (const float*)d_in[8];
    const float* bv = (const float*)d_in[9];
    const float* w2 = (const float*)d_in[10];
    const float* b2 = (const float*)d_in[11];
    float* outp = (float*)d_out;

    int n = in_sizes[0] / 256;
    int E = in_sizes[1] / 2;

    float* ws = (float*)d_ws;
    size_t off = 0;
    float* dinv = ws + off; off += (size_t)n;
    float* q    = ws + off; off += (size_t)n * 64;
    float* K    = ws + off; off += (size_t)n * 64 * NUM_LAYERS;
    float* V    = ws + off; off += (size_t)n * 64 * NUM_LAYERS;
    float* xs   = ws + off; off += (size_t)n * 64 * (NUM_LAYERS + 1);
    int* wsI    = (int*)(ws + off);
    int* counts = wsI;                 // n
    int* fill   = wsI + n;             // n
    int* startA = wsI + 2 * n;         // n+1
    int* ebuf   = wsI + 3 * n + 1;     // E

    // CSR build (counts+fill zeroed in one memset)
    hipMemsetAsync(counts, 0, 2 * (size_t)n * sizeof(int), stream);
    k_count<<<(E + 255) / 256, 256, 0, stream>>>(ei + E, counts, E);
    k_scan<<<1, 1024, 0, stream>>>(counts, startA, dinv, n);
    k_scatter<<<(E + 255) / 256, 256, 0, stream>>>(ei, startA, fill, ebuf, E);

    k_lin1<<<(n + 63) / 64, 256, 0, stream>>>(x, w1, b1, xs, n);

    int attn_grid = (int)(((size_t)n * 64 + 255) / 256);
    for (int l = 0; l < NUM_LAYERS; ++l) {
        int t = l + 1;
        // layer 0: only V needed (softmax over 1 element == 1)
        int job_offset = (l == 0) ? 2 : 0;
        int njobs      = (l == 0) ? 1 : 1 + 2 * t;
        dim3 grid((n + 63) / 64, njobs);
        k_qkv<<<grid, 256, 0, stream>>>(xs, wq, bq, wk, bk, wv, bv,
                                        q, K, V, n, l, t, job_offset);
        float* dst = xs + (size_t)(l + 1) * n * 64;
        if (t == 1)
            k_attn_g<1><<<attn_grid, 256, 0, stream>>>(startA, ebuf, dinv, q, K, V, dst, n);
        else if (t == 2)
            k_attn_g<2><<<attn_grid, 256, 0, stream>>>(startA, ebuf, dinv, q, K, V, dst, n);
        else
            k_attn_g<3><<<attn_grid, 256, 0, stream>>>(startA, ebuf, dinv, q, K, V, dst, n);
    }

    k_final<<<((int)(((long long)n * 64 + 255) / 256)), 256, 0, stream>>>(
        xs + (size_t)NUM_LAYERS * n * 64, w2, b2, outp, n);
}

// Round 5
// 297.180 us; speedup vs baseline: 2.3008x; 1.1994x over previous
//
#include <hip/hip_runtime.h>
#include <math.h>

#define HID 64
#define HEADS 8
#define NUM_LAYERS 3

// ---------------------------------------------------------------------------
// bf16 helpers (storage-only compression of K/V; math stays f32)
// ---------------------------------------------------------------------------
__device__ __forceinline__ unsigned short f2bf(float f) {
    union { float f; unsigned int u; } cv; cv.f = f;
    unsigned int u = cv.u;
    unsigned int r = (u + 0x7FFFu + ((u >> 16) & 1u)) >> 16;  // RNE
    return (unsigned short)r;
}
__device__ __forceinline__ float bflo(unsigned int u) {
    union { unsigned int u; float f; } cv; cv.u = u << 16; return cv.f;
}
__device__ __forceinline__ float bfhi(unsigned int u) {
    union { unsigned int u; float f; } cv; cv.u = u & 0xFFFF0000u; return cv.f;
}

// ---------------------------------------------------------------------------
// CSR build: counts (atomic), scan+dinv (single block), scatter
// ---------------------------------------------------------------------------
__global__ void k_count(const int* __restrict__ col, int* __restrict__ counts, int E) {
    int e = blockIdx.x * blockDim.x + threadIdx.x;
    if (e < E) atomicAdd(&counts[col[e]], 1);
}

__global__ __launch_bounds__(1024) void k_scan(const int* __restrict__ counts,
                                               int* __restrict__ start,
                                               float* __restrict__ dinv, int n) {
    __shared__ int wsum[16];
    __shared__ int carry_s;
    int tid = threadIdx.x;
    int lane = tid & 63, wv = tid >> 6;
    if (tid == 0) carry_s = 0;
    __syncthreads();
    for (int base = 0; base < n; base += 1024) {
        int i = base + tid;
        int v = (i < n) ? counts[i] : 0;
        int x = v;
#pragma unroll
        for (int off = 1; off < 64; off <<= 1) {
            int y = __shfl_up(x, off);
            if (lane >= off) x += y;
        }
        if (lane == 63) wsum[wv] = x;
        __syncthreads();
        if (wv == 0 && lane < 16) {
            int s = wsum[lane];
#pragma unroll
            for (int off = 1; off < 16; off <<= 1) {
                int y = __shfl_up(s, off);
                if (lane >= off) s += y;
            }
            wsum[lane] = s;
        }
        __syncthreads();
        int waveoff = (wv > 0) ? wsum[wv - 1] : 0;
        int carry = carry_s;
        if (i < n) {
            start[i] = carry + waveoff + x - v;   // exclusive prefix
            dinv[i] = rsqrtf((float)(v + 1));     // +1 self-loop
        }
        __syncthreads();
        if (tid == 0) carry_s = carry + wsum[15];
        __syncthreads();
    }
    if (threadIdx.x == 0) start[n] = carry_s;
}

__global__ void k_scatter(const int* __restrict__ ei, const int* __restrict__ start,
                          int* __restrict__ fill, int* __restrict__ ebuf, int E) {
    int e = blockIdx.x * blockDim.x + threadIdx.x;
    if (e >= E) return;
    int r = ei[e], c = ei[E + e];
    int pos = start[c] + atomicAdd(&fill[c], 1);
    ebuf[pos] = r;
}

// ---------------------------------------------------------------------------
// Register-tiled GEMM building block: 64x64 tile, 256 threads, 4x4 acc.
// ---------------------------------------------------------------------------
#define ST_STRIDE 68

__device__ __forceinline__ void gemm_tile_stage_src(
    float* st, const float* __restrict__ src, int node0, int n, int ld,
    int kc, bool relu_in, int tid) {
    int nd = tid >> 4;             // 0..15
    int c4 = (tid & 15) * 4;       // 0..60
#pragma unroll
    for (int rep = 0; rep < 4; ++rep) {
        int lnode = nd + rep * 16;
        int node = node0 + lnode;
        float4 v = make_float4(0.f, 0.f, 0.f, 0.f);
        if (node < n) v = *(const float4*)&src[(size_t)node * ld + kc + c4];
        if (relu_in) {
            v.x = fmaxf(v.x, 0.f); v.y = fmaxf(v.y, 0.f);
            v.z = fmaxf(v.z, 0.f); v.w = fmaxf(v.w, 0.f);
        }
        st[(c4 + 0) * ST_STRIDE + lnode] = v.x;
        st[(c4 + 1) * ST_STRIDE + lnode] = v.y;
        st[(c4 + 2) * ST_STRIDE + lnode] = v.z;
        st[(c4 + 3) * ST_STRIDE + lnode] = v.w;
    }
}

__device__ __forceinline__ void gemm_tile_inner(
    const float* st, const float* wl, int ri, int j, float acc[4][4]) {
#pragma unroll 4
    for (int c = 0; c < 64; ++c) {
        float4 a  = *(const float4*)&st[c * ST_STRIDE + ri * 4];
        float4 b4 = *(const float4*)&wl[c * 64 + j * 4];
        acc[0][0] += a.x * b4.x; acc[0][1] += a.x * b4.y;
        acc[0][2] += a.x * b4.z; acc[0][3] += a.x * b4.w;
        acc[1][0] += a.y * b4.x; acc[1][1] += a.y * b4.y;
        acc[1][2] += a.y * b4.z; acc[1][3] += a.y * b4.w;
        acc[2][0] += a.z * b4.x; acc[2][1] += a.z * b4.y;
        acc[2][2] += a.z * b4.z; acc[2][3] += a.z * b4.w;
        acc[3][0] += a.w * b4.x; acc[3][1] += a.w * b4.y;
        acc[3][2] += a.w * b4.z; acc[3][3] += a.w * b4.w;
    }
}

// ---------------------------------------------------------------------------
// lin1: h = relu(x @ W1 + b1), K = 256 chunked by 64.
// ---------------------------------------------------------------------------
__global__ __launch_bounds__(256, 4) void k_lin1(const float* __restrict__ x,
                                                 const float* __restrict__ w,
                                                 const float* __restrict__ b,
                                                 float* __restrict__ h, int n) {
    __shared__ float wl[64 * 64];
    __shared__ float st[64 * ST_STRIDE];
    int tid = threadIdx.x;
    int node0 = blockIdx.x * 64;
    int ri = tid >> 4, j = tid & 15;
    float acc[4][4];
#pragma unroll
    for (int m = 0; m < 4; ++m)
#pragma unroll
        for (int k = 0; k < 4; ++k) acc[m][k] = 0.f;

    for (int kc = 0; kc < 256; kc += 64) {
        for (int i = tid * 4; i < 4096; i += 1024)
            *(float4*)&wl[i] = *(const float4*)&w[kc * 64 + i];
        gemm_tile_stage_src(st, x, node0, n, 256, kc, false, tid);
        __syncthreads();
        gemm_tile_inner(st, wl, ri, j, acc);
        __syncthreads();
    }
    float4 bb = *(const float4*)&b[j * 4];
#pragma unroll
    for (int m = 0; m < 4; ++m) {
        int node = node0 + ri * 4 + m;
        if (node < n) {
            float4 o = make_float4(fmaxf(acc[m][0] + bb.x, 0.f),
                                   fmaxf(acc[m][1] + bb.y, 0.f),
                                   fmaxf(acc[m][2] + bb.z, 0.f),
                                   fmaxf(acc[m][3] + bb.w, 0.f));
            *(float4*)&h[(size_t)node * 64 + j * 4] = o;
        }
    }
}

// ---------------------------------------------------------------------------
// batched 64x64 GEMM for q / K / V of one layer (register-tiled).
// job (blockIdx.y + job_offset): 0 -> q (f32), 1..t -> K slice s (bf16 kv),
// t+1..2t -> V slice s (bf16 kv).  kv layout: [node][s][K64|V64] bf16,
// stride kv_stride (=t*128; t==1: 64, V only at offset 0).
// ---------------------------------------------------------------------------
__global__ __launch_bounds__(256, 4) void k_qkv(
    const float* __restrict__ xsbase,
    const float* __restrict__ wq, const float* __restrict__ bq,
    const float* __restrict__ wk, const float* __restrict__ bk,
    const float* __restrict__ wv, const float* __restrict__ bv,
    float* __restrict__ q, unsigned short* __restrict__ kv,
    int n, int layer, int t, int job_offset, int kv_stride) {
    int job = blockIdx.y + job_offset;
    const float* src; const float* w; const float* b; bool relu_in;
    int kv_off = 0;
    if (job == 0) {
        src = xsbase + (size_t)layer * n * 64;
        w = wq + layer * 4096; b = bq + layer * 64;
        relu_in = (layer >= 1);
    } else if (job <= t) {
        int s = job - 1;
        src = xsbase + (size_t)s * n * 64;
        w = wk + layer * 4096; b = bk + layer * 64;
        kv_off = s * 128;
        relu_in = (s >= 1);
    } else {
        int s = job - t - 1;
        src = xsbase + (size_t)s * n * 64;
        w = wv + layer * 4096; b = bv + layer * 64;
        kv_off = (t == 1) ? 0 : s * 128 + 64;
        relu_in = (s >= 1);
    }
    __shared__ float wl[64 * 64];
    __shared__ float st[64 * ST_STRIDE];
    int tid = threadIdx.x;
    int node0 = blockIdx.x * 64;
    for (int i = tid * 4; i < 4096; i += 1024)
        *(float4*)&wl[i] = *(const float4*)&w[i];
    gemm_tile_stage_src(st, src, node0, n, 64, 0, relu_in, tid);
    __syncthreads();
    int ri = tid >> 4, j = tid & 15;
    float acc[4][4];
#pragma unroll
    for (int m = 0; m < 4; ++m)
#pragma unroll
        for (int k = 0; k < 4; ++k) acc[m][k] = 0.f;
    gemm_tile_inner(st, wl, ri, j, acc);
    float4 bb = *(const float4*)&b[j * 4];
    if (job == 0) {
#pragma unroll
        for (int m = 0; m < 4; ++m) {
            int node = node0 + ri * 4 + m;
            if (node < n) {
                float4 o = make_float4(acc[m][0] + bb.x, acc[m][1] + bb.y,
                                       acc[m][2] + bb.z, acc[m][3] + bb.w);
                *(float4*)&q[(size_t)node * 64 + j * 4] = o;
            }
        }
    } else {
#pragma unroll
        for (int m = 0; m < 4; ++m) {
            int node = node0 + ri * 4 + m;
            if (node < n) {
                ushort4 o;
                o.x = f2bf(acc[m][0] + bb.x);
                o.y = f2bf(acc[m][1] + bb.y);
                o.z = f2bf(acc[m][2] + bb.z);
                o.w = f2bf(acc[m][3] + bb.w);
                *(ushort4*)&kv[(size_t)node * kv_stride + kv_off + j * 4] = o;
            }
        }
    }
}

// ---------------------------------------------------------------------------
// attention + aggregate, CSR by destination.  One wave per node.
// Lane = (edge-slot g = lane>>3, head h = lane&7): 8 edges in flight,
// lane-local dot/softmax.  K/V read as bf16 (one dwordx4 per slice per lane).
// T==1: softmax == 1 -> pure dinv-weighted V gather (kv stride 64).
// ---------------------------------------------------------------------------
template <int T>
__global__ __launch_bounds__(256) void k_attn_g(
    const int* __restrict__ start, const int* __restrict__ ebuf,
    const float* __restrict__ dinv, const float* __restrict__ q,
    const unsigned short* __restrict__ kv, float* __restrict__ outp, int n) {
    const int KVS = (T == 1) ? 64 : T * 128;
    int node = (int)((blockIdx.x * (size_t)blockDim.x + threadIdx.x) >> 6);
    int lane = threadIdx.x & 63;
    if (node >= n) return;
    int g = lane >> 3;        // edge slot 0..7
    int cb = (lane & 7) * 8;  // channel base for this head
    const float isd = 0.35355339059327373f;  // 1/sqrt(8)

    float qv[8];
    if (T > 1) {
        float4 q0 = *(const float4*)&q[(size_t)node * 64 + cb];
        float4 q1 = *(const float4*)&q[(size_t)node * 64 + cb + 4];
        qv[0] = q0.x; qv[1] = q0.y; qv[2] = q0.z; qv[3] = q0.w;
        qv[4] = q1.x; qv[5] = q1.y; qv[6] = q1.z; qv[7] = q1.w;
    }
    float dc = dinv[node];
    int s0 = start[node];
    int cnt = start[node + 1] - s0 + 1;  // + self-loop (item 0)

    float acc[8];
#pragma unroll
    for (int k = 0; k < 8; ++k) acc[k] = 0.f;

    for (int base = 0; base < cnt; base += 8) {
        int idx = base + g;
        bool valid = idx < cnt;
        int r = node;                      // item 0 = self-loop
        if (valid && idx > 0) r = ebuf[s0 + idx - 1];
        float dr = valid ? dinv[r] : 0.f;  // invalid slots contribute 0
        const unsigned short* rkv = kv + (size_t)r * KVS;

        float sc[T];
        float wgt;
        if (T > 1) {
            float m = -1e30f;
#pragma unroll
            for (int s = 0; s < T; ++s) {
                uint4 ku = *(const uint4*)&rkv[s * 128 + cb];
                float p = qv[0] * bflo(ku.x) + qv[1] * bfhi(ku.x)
                        + qv[2] * bflo(ku.y) + qv[3] * bfhi(ku.y)
                        + qv[4] * bflo(ku.z) + qv[5] * bfhi(ku.z)
                        + qv[6] * bflo(ku.w) + qv[7] * bfhi(ku.w);
                p *= isd;
                sc[s] = p;
                m = fmaxf(m, p);
            }
            float denom = 0.f;
#pragma unroll
            for (int s = 0; s < T; ++s) { sc[s] = __expf(sc[s] - m); denom += sc[s]; }
            wgt = dr / denom;
        } else {
            sc[0] = 1.f;
            wgt = dr;
        }

        float mg[8];
#pragma unroll
        for (int k = 0; k < 8; ++k) mg[k] = 0.f;
#pragma unroll
        for (int s = 0; s < T; ++s) {
            uint4 vu = *(const uint4*)&rkv[((T == 1) ? 0 : s * 128 + 64) + cb];
            float wv_ = sc[s];
            mg[0] += wv_ * bflo(vu.x); mg[1] += wv_ * bfhi(vu.x);
            mg[2] += wv_ * bflo(vu.y); mg[3] += wv_ * bfhi(vu.y);
            mg[4] += wv_ * bflo(vu.z); mg[5] += wv_ * bfhi(vu.z);
            mg[6] += wv_ * bflo(vu.w); mg[7] += wv_ * bfhi(vu.w);
        }
#pragma unroll
        for (int k = 0; k < 8; ++k) acc[k] += wgt * mg[k];
    }

#pragma unroll
    for (int off = 8; off < 64; off <<= 1) {
#pragma unroll
        for (int k = 0; k < 8; ++k) acc[k] += __shfl_xor(acc[k], off);
    }
    if (g == 0) {
        float4 o0 = make_float4(acc[0] * dc, acc[1] * dc, acc[2] * dc, acc[3] * dc);
        float4 o1 = make_float4(acc[4] * dc, acc[5] * dc, acc[6] * dc, acc[7] * dc);
        *(float4*)&outp[(size_t)node * 64 + cb] = o0;
        *(float4*)&outp[(size_t)node * 64 + cb + 4] = o1;
    }
}

// ---------------------------------------------------------------------------
// final: logits = relu(x3) @ W2 + b2 -> log_softmax. One wave per node.
// ---------------------------------------------------------------------------
__global__ __launch_bounds__(256) void k_final(
    const float* __restrict__ x3, const float* __restrict__ w,
    const float* __restrict__ b, float* __restrict__ outp, int n) {
    int wid  = (int)((blockIdx.x * (size_t)blockDim.x + threadIdx.x) >> 6);
    int lane = threadIdx.x & 63;
    if (wid >= n) return;
    float xv = fmaxf(x3[(size_t)wid * 64 + lane], 0.f);
    float acc = b[lane];
#pragma unroll
    for (int c = 0; c < 64; ++c) {
        float xc = __shfl(xv, c);
        acc += xc * w[c * 64 + lane];
    }
    float m = acc;
    for (int off = 1; off < 64; off <<= 1) m = fmaxf(m, __shfl_xor(m, off));
    float e = __expf(acc - m);
    float ssum = e;
    for (int off = 1; off < 64; off <<= 1) ssum += __shfl_xor(ssum, off);
    outp[(size_t)wid * 64 + lane] = acc - m - __logf(ssum);
}

// ---------------------------------------------------------------------------
extern "C" void kernel_launch(void* const* d_in, const int* in_sizes, int n_in,
                              void* d_out, int out_size, void* d_ws, size_t ws_size,
                              hipStream_t stream) {
    const float* x  = (const float*)d_in[0];
    const int*   ei = (const int*)d_in[1];
    const float* w1 = (const float*)d_in[2];
    const float* b1 = (const float*)d_in[3];
    const float* wq = (const float*)d_in[4];
    const float* bq = (const float*)d_in[5];
    const float* wk = (const float*)d_in[6];
    const float* bk = (const float*)d_in[7];
    const float* wv = (const float*)d_in[8];
    const float* bv = (const float*)d_in[9];
    const float* w2 = (const float*)d_in[10];
    const float* b2 = (const float*)d_in[11];
    float* outp = (float*)d_out;

    int n = in_sizes[0] / 256;
    int E = in_sizes[1] / 2;

    float* ws = (float*)d_ws;
    size_t off = 0;
    float* dinv = ws + off; off += (size_t)n;
    float* q    = ws + off; off += (size_t)n * 64;
    float* xs   = ws + off; off += (size_t)n * 64 * (NUM_LAYERS + 1);
    unsigned short* kvU = (unsigned short*)(ws + off); off += (size_t)n * 192;  // n*384 ushort
    int* wsI    = (int*)(ws + off);
    int* counts = wsI;                 // n
    int* fill   = wsI + n;             // n
    int* startA = wsI + 2 * n;         // n+1
    int* ebuf   = wsI + 3 * n + 1;     // E

    // CSR build (counts+fill zeroed in one memset)
    hipMemsetAsync(counts, 0, 2 * (size_t)n * sizeof(int), stream);
    k_count<<<(E + 255) / 256, 256, 0, stream>>>(ei + E, counts, E);
    k_scan<<<1, 1024, 0, stream>>>(counts, startA, dinv, n);
    k_scatter<<<(E + 255) / 256, 256, 0, stream>>>(ei, startA, fill, ebuf, E);

    k_lin1<<<(n + 63) / 64, 256, 0, stream>>>(x, w1, b1, xs, n);

    int attn_grid = (int)(((size_t)n * 64 + 255) / 256);
    for (int l = 0; l < NUM_LAYERS; ++l) {
        int t = l + 1;
        // layer 0: only V needed (softmax over 1 element == 1)
        int job_offset = (l == 0) ? 2 : 0;
        int njobs      = (l == 0) ? 1 : 1 + 2 * t;
        int kv_stride  = (t == 1) ? 64 : t * 128;
        dim3 grid((n + 63) / 64, njobs);
        k_qkv<<<grid, 256, 0, stream>>>(xs, wq, bq, wk, bk, wv, bv,
                                        q, kvU, n, l, t, job_offset, kv_stride);
        float* dst = xs + (size_t)(l + 1) * n * 64;
        if (t == 1)
            k_attn_g<1><<<attn_grid, 256, 0, stream>>>(startA, ebuf, dinv, q, kvU, dst, n);
        else if (t == 2)
            k_attn_g<2><<<attn_grid, 256, 0, stream>>>(startA, ebuf, dinv, q, kvU, dst, n);
        else
            k_attn_g<3><<<attn_grid, 256, 0, stream>>>(startA, ebuf, dinv, q, kvU, dst, n);
    }

    k_final<<<((int)(((long long)n * 64 + 255) / 256)), 256, 0, stream>>>(
        xs + (size_t)NUM_LAYERS * n * 64, w2, b2, outp, n);
}

// Round 6
// 267.305 us; speedup vs baseline: 2.5580x; 1.1118x over previous
//
#include <hip/hip_runtime.h>
#include <math.h>

#define HID 64
#define HEADS 8
#define NUM_LAYERS 3

typedef __attribute__((ext_vector_type(8))) short bf16x8;
typedef __attribute__((ext_vector_type(4))) float f32x4;

// ---------------------------------------------------------------------------
// bf16 helpers (storage compression; accumulation stays f32)
// ---------------------------------------------------------------------------
__device__ __forceinline__ unsigned short f2bf(float f) {
    union { float f; unsigned int u; } cv; cv.f = f;
    unsigned int u = cv.u;
    unsigned int r = (u + 0x7FFFu + ((u >> 16) & 1u)) >> 16;  // RNE
    return (unsigned short)r;
}
__device__ __forceinline__ float bflo(unsigned int u) {
    union { unsigned int u; float f; } cv; cv.u = u << 16; return cv.f;
}
__device__ __forceinline__ float bfhi(unsigned int u) {
    union { unsigned int u; float f; } cv; cv.u = u & 0xFFFF0000u; return cv.f;
}
__device__ __forceinline__ unsigned relu_pk(unsigned u) {  // relu on 2 packed bf16
    unsigned m = ((u & 0x8000u) ? 0u : 0xFFFFu) |
                 ((u & 0x80000000u) ? 0u : 0xFFFF0000u);
    return u & m;
}

// ---------------------------------------------------------------------------
// CSR build: counts (atomic), scan+dinv (single block), scatter
// ---------------------------------------------------------------------------
__global__ void k_count(const int* __restrict__ col, int* __restrict__ counts, int E) {
    int e = blockIdx.x * blockDim.x + threadIdx.x;
    if (e < E) atomicAdd(&counts[col[e]], 1);
}

__global__ __launch_bounds__(1024) void k_scan(const int* __restrict__ counts,
                                               int* __restrict__ start,
                                               float* __restrict__ dinv, int n) {
    __shared__ int wsum[16];
    __shared__ int carry_s;
    int tid = threadIdx.x;
    int lane = tid & 63, wv = tid >> 6;
    if (tid == 0) carry_s = 0;
    __syncthreads();
    for (int base = 0; base < n; base += 1024) {
        int i = base + tid;
        int v = (i < n) ? counts[i] : 0;
        int x = v;
#pragma unroll
        for (int off = 1; off < 64; off <<= 1) {
            int y = __shfl_up(x, off);
            if (lane >= off) x += y;
        }
        if (lane == 63) wsum[wv] = x;
        __syncthreads();
        if (wv == 0 && lane < 16) {
            int s = wsum[lane];
#pragma unroll
            for (int off = 1; off < 16; off <<= 1) {
                int y = __shfl_up(s, off);
                if (lane >= off) s += y;
            }
            wsum[lane] = s;
        }
        __syncthreads();
        int waveoff = (wv > 0) ? wsum[wv - 1] : 0;
        int carry = carry_s;
        if (i < n) {
            start[i] = carry + waveoff + x - v;   // exclusive prefix
            dinv[i] = rsqrtf((float)(v + 1));     // +1 self-loop
        }
        __syncthreads();
        if (tid == 0) carry_s = carry + wsum[15];
        __syncthreads();
    }
    if (threadIdx.x == 0) start[n] = carry_s;
}

__global__ void k_scatter(const int* __restrict__ ei, const int* __restrict__ start,
                          int* __restrict__ fill, int* __restrict__ ebuf, int E) {
    int e = blockIdx.x * blockDim.x + threadIdx.x;
    if (e >= E) return;
    int r = ei[e], c = ei[E + e];
    int pos = start[c] + atomicAdd(&fill[c], 1);
    ebuf[pos] = r;
}

// ---------------------------------------------------------------------------
// MFMA GEMM core: block = 64 nodes x 64 oc, 4 waves, wave w = 16-row strip.
// A in LDS row-major bf16 (stride 72: 2-way-conflict-free, 16B aligned);
// W in LDS transposed bf16 [n][k] (B-frag reads contiguous in k).
// A-frag: A[m=lane&15][k=quad*8+j]; C/D: col=lane&15, row=quad*4+reg (m89/m91).
// ---------------------------------------------------------------------------
#define ALD 72

__device__ __forceinline__ void stage_w_bf16(unsigned short* Wt,
                                             const float* __restrict__ w, int tid) {
    for (int idx = tid; idx < 1024; idx += 256) {
        int k = idx >> 4, n4 = (idx & 15) * 4;
        float4 wv = *(const float4*)&w[k * 64 + n4];
        Wt[(n4 + 0) * ALD + k] = f2bf(wv.x);
        Wt[(n4 + 1) * ALD + k] = f2bf(wv.y);
        Wt[(n4 + 2) * ALD + k] = f2bf(wv.z);
        Wt[(n4 + 3) * ALD + k] = f2bf(wv.w);
    }
}

__device__ __forceinline__ void mfma_step(const unsigned short* Alds,
                                          const unsigned short* Wt,
                                          int tid, f32x4 acc[4]) {
    int lane = tid & 63;
    int m0 = (tid >> 6) * 16;
    int c16 = lane & 15, quad = lane >> 4;
    const unsigned short* ar = &Alds[(m0 + c16) * ALD + quad * 8];
    bf16x8 a0 = *(const bf16x8*)ar;
    bf16x8 a1 = *(const bf16x8*)(ar + 32);
#pragma unroll
    for (int nt = 0; nt < 4; ++nt) {
        const unsigned short* br = &Wt[(nt * 16 + c16) * ALD + quad * 8];
        bf16x8 b0 = *(const bf16x8*)br;
        bf16x8 b1 = *(const bf16x8*)(br + 32);
        acc[nt] = __builtin_amdgcn_mfma_f32_16x16x32_bf16(a0, b0, acc[nt], 0, 0, 0);
        acc[nt] = __builtin_amdgcn_mfma_f32_16x16x32_bf16(a1, b1, acc[nt], 0, 0, 0);
    }
}

// ---------------------------------------------------------------------------
// lin1: h = relu(x @ W1 + b1) -> bf16.  K=256 in 4 chunks of 64.
// ---------------------------------------------------------------------------
__global__ __launch_bounds__(256, 4) void k_lin1(const float* __restrict__ x,
                                                 const float* __restrict__ w,
                                                 const float* __restrict__ b,
                                                 unsigned short* __restrict__ h, int n) {
    __shared__ __align__(16) unsigned short Alds[64 * ALD];
    __shared__ __align__(16) unsigned short Wt[64 * ALD];
    int tid = threadIdx.x;
    int node0 = blockIdx.x * 64;
    f32x4 acc[4];
#pragma unroll
    for (int nt = 0; nt < 4; ++nt) acc[nt] = (f32x4){0.f, 0.f, 0.f, 0.f};

    for (int kc = 0; kc < 256; kc += 64) {
        __syncthreads();
        stage_w_bf16(Wt, w + kc * 64, tid);
        for (int idx = tid; idx < 1024; idx += 256) {
            int r = idx >> 4, c4 = (idx & 15) * 4;
            int node = node0 + r;
            float4 v = make_float4(0.f, 0.f, 0.f, 0.f);
            if (node < n) v = *(const float4*)&x[(size_t)node * 256 + kc + c4];
            Alds[r * ALD + c4 + 0] = f2bf(v.x);
            Alds[r * ALD + c4 + 1] = f2bf(v.y);
            Alds[r * ALD + c4 + 2] = f2bf(v.z);
            Alds[r * ALD + c4 + 3] = f2bf(v.w);
        }
        __syncthreads();
        mfma_step(Alds, Wt, tid, acc);
    }
    int lane = tid & 63;
    int m0 = (tid >> 6) * 16, c16 = lane & 15, quad = lane >> 4;
    float bias[4];
#pragma unroll
    for (int nt = 0; nt < 4; ++nt) bias[nt] = b[nt * 16 + c16];
#pragma unroll
    for (int i = 0; i < 4; ++i) {
        int node = node0 + m0 + quad * 4 + i;
        if (node < n) {
#pragma unroll
            for (int nt = 0; nt < 4; ++nt) {
                float o = acc[nt][i] + bias[nt];
                h[(size_t)node * 64 + nt * 16 + c16] = f2bf(fmaxf(o, 0.f));
            }
        }
    }
}

// ---------------------------------------------------------------------------
// batched 64x64 MFMA GEMM for q / K / V of one layer.
// job (blockIdx.y + job_offset): 0 -> q (f32), 1..t -> K slice s (bf16 kv),
// t+1..2t -> V slice s (bf16 kv).  kv layout [node][s][K64|V64], stride
// kv_stride (t*128; t==1: 64, V only).  src slices are bf16; s>=1 raw
// (relu applied while staging).
// ---------------------------------------------------------------------------
__global__ __launch_bounds__(256, 4) void k_qkv(
    const unsigned short* __restrict__ xsbase,
    const float* __restrict__ wq, const float* __restrict__ bq,
    const float* __restrict__ wk, const float* __restrict__ bk,
    const float* __restrict__ wv, const float* __restrict__ bv,
    float* __restrict__ q, unsigned short* __restrict__ kv,
    int n, int layer, int t, int job_offset, int kv_stride) {
    int job = blockIdx.y + job_offset;
    const unsigned short* src; const float* w; const float* b; bool relu_in;
    int kv_off = 0;
    if (job == 0) {
        src = xsbase + (size_t)layer * n * 64;
        w = wq + layer * 4096; b = bq + layer * 64;
        relu_in = (layer >= 1);
    } else if (job <= t) {
        int s = job - 1;
        src = xsbase + (size_t)s * n * 64;
        w = wk + layer * 4096; b = bk + layer * 64;
        kv_off = s * 128;
        relu_in = (s >= 1);
    } else {
        int s = job - t - 1;
        src = xsbase + (size_t)s * n * 64;
        w = wv + layer * 4096; b = bv + layer * 64;
        kv_off = (t == 1) ? 0 : s * 128 + 64;
        relu_in = (s >= 1);
    }
    __shared__ __align__(16) unsigned short Alds[64 * ALD];
    __shared__ __align__(16) unsigned short Wt[64 * ALD];
    int tid = threadIdx.x;
    int node0 = blockIdx.x * 64;
    stage_w_bf16(Wt, w, tid);
    for (int idx = tid; idx < 512; idx += 256) {
        int r = idx >> 3, seg = idx & 7;
        int node = node0 + r;
        uint4 u = make_uint4(0u, 0u, 0u, 0u);
        if (node < n) u = *(const uint4*)&src[(size_t)node * 64 + seg * 8];
        if (relu_in) {
            u.x = relu_pk(u.x); u.y = relu_pk(u.y);
            u.z = relu_pk(u.z); u.w = relu_pk(u.w);
        }
        *(uint4*)&Alds[r * ALD + seg * 8] = u;
    }
    __syncthreads();
    f32x4 acc[4];
#pragma unroll
    for (int nt = 0; nt < 4; ++nt) acc[nt] = (f32x4){0.f, 0.f, 0.f, 0.f};
    mfma_step(Alds, Wt, tid, acc);

    int lane = tid & 63;
    int m0 = (tid >> 6) * 16, c16 = lane & 15, quad = lane >> 4;
    float bias[4];
#pragma unroll
    for (int nt = 0; nt < 4; ++nt) bias[nt] = b[nt * 16 + c16];
    if (job == 0) {
#pragma unroll
        for (int i = 0; i < 4; ++i) {
            int node = node0 + m0 + quad * 4 + i;
            if (node < n) {
#pragma unroll
                for (int nt = 0; nt < 4; ++nt)
                    q[(size_t)node * 64 + nt * 16 + c16] = acc[nt][i] + bias[nt];
            }
        }
    } else {
#pragma unroll
        for (int i = 0; i < 4; ++i) {
            int node = node0 + m0 + quad * 4 + i;
            if (node < n) {
#pragma unroll
                for (int nt = 0; nt < 4; ++nt)
                    kv[(size_t)node * kv_stride + kv_off + nt * 16 + c16] =
                        f2bf(acc[nt][i] + bias[nt]);
            }
        }
    }
}

// ---------------------------------------------------------------------------
// attention + aggregate, CSR by destination.  One wave per node.
// Lane = (edge-slot g = lane>>3, head h = lane&7): 8 edges in flight,
// lane-local dot/softmax.  K/V bf16; output stored bf16 (xs slice).
// T==1: softmax == 1 -> pure dinv-weighted V gather (kv stride 64).
// ---------------------------------------------------------------------------
template <int T>
__global__ __launch_bounds__(256) void k_attn_g(
    const int* __restrict__ start, const int* __restrict__ ebuf,
    const float* __restrict__ dinv, const float* __restrict__ q,
    const unsigned short* __restrict__ kv, unsigned short* __restrict__ outp, int n) {
    const int KVS = (T == 1) ? 64 : T * 128;
    int node = (int)((blockIdx.x * (size_t)blockDim.x + threadIdx.x) >> 6);
    int lane = threadIdx.x & 63;
    if (node >= n) return;
    int g = lane >> 3;        // edge slot 0..7
    int cb = (lane & 7) * 8;  // channel base for this head
    const float isd = 0.35355339059327373f;  // 1/sqrt(8)

    float qv[8];
    if (T > 1) {
        float4 q0 = *(const float4*)&q[(size_t)node * 64 + cb];
        float4 q1 = *(const float4*)&q[(size_t)node * 64 + cb + 4];
        qv[0] = q0.x; qv[1] = q0.y; qv[2] = q0.z; qv[3] = q0.w;
        qv[4] = q1.x; qv[5] = q1.y; qv[6] = q1.z; qv[7] = q1.w;
    }
    float dc = dinv[node];
    int s0 = start[node];
    int cnt = start[node + 1] - s0 + 1;  // + self-loop (item 0)

    float acc[8];
#pragma unroll
    for (int k = 0; k < 8; ++k) acc[k] = 0.f;

    for (int base = 0; base < cnt; base += 8) {
        int idx = base + g;
        bool valid = idx < cnt;
        int r = node;                      // item 0 = self-loop
        if (valid && idx > 0) r = ebuf[s0 + idx - 1];
        float dr = valid ? dinv[r] : 0.f;  // invalid slots contribute 0
        const unsigned short* rkv = kv + (size_t)r * KVS;

        float sc[T];
        float wgt;
        if (T > 1) {
            float m = -1e30f;
#pragma unroll
            for (int s = 0; s < T; ++s) {
                uint4 ku = *(const uint4*)&rkv[s * 128 + cb];
                float p = qv[0] * bflo(ku.x) + qv[1] * bfhi(ku.x)
                        + qv[2] * bflo(ku.y) + qv[3] * bfhi(ku.y)
                        + qv[4] * bflo(ku.z) + qv[5] * bfhi(ku.z)
                        + qv[6] * bflo(ku.w) + qv[7] * bfhi(ku.w);
                p *= isd;
                sc[s] = p;
                m = fmaxf(m, p);
            }
            float denom = 0.f;
#pragma unroll
            for (int s = 0; s < T; ++s) { sc[s] = __expf(sc[s] - m); denom += sc[s]; }
            wgt = dr / denom;
        } else {
            sc[0] = 1.f;
            wgt = dr;
        }

        float mg[8];
#pragma unroll
        for (int k = 0; k < 8; ++k) mg[k] = 0.f;
#pragma unroll
        for (int s = 0; s < T; ++s) {
            uint4 vu = *(const uint4*)&rkv[((T == 1) ? 0 : s * 128 + 64) + cb];
            float wv_ = sc[s];
            mg[0] += wv_ * bflo(vu.x); mg[1] += wv_ * bfhi(vu.x);
            mg[2] += wv_ * bflo(vu.y); mg[3] += wv_ * bfhi(vu.y);
            mg[4] += wv_ * bflo(vu.z); mg[5] += wv_ * bfhi(vu.z);
            mg[6] += wv_ * bflo(vu.w); mg[7] += wv_ * bfhi(vu.w);
        }
#pragma unroll
        for (int k = 0; k < 8; ++k) acc[k] += wgt * mg[k];
    }

#pragma unroll
    for (int off = 8; off < 64; off <<= 1) {
#pragma unroll
        for (int k = 0; k < 8; ++k) acc[k] += __shfl_xor(acc[k], off);
    }
    if (g == 0) {
        ushort4 o0, o1;
        o0.x = f2bf(acc[0] * dc); o0.y = f2bf(acc[1] * dc);
        o0.z = f2bf(acc[2] * dc); o0.w = f2bf(acc[3] * dc);
        o1.x = f2bf(acc[4] * dc); o1.y = f2bf(acc[5] * dc);
        o1.z = f2bf(acc[6] * dc); o1.w = f2bf(acc[7] * dc);
        *(ushort4*)&outp[(size_t)node * 64 + cb] = o0;
        *(ushort4*)&outp[(size_t)node * 64 + cb + 4] = o1;
    }
}

// ---------------------------------------------------------------------------
// final: logits = relu(x3) @ W2 + b2 -> log_softmax.  One wave per node;
// x3 is bf16.
// ---------------------------------------------------------------------------
__global__ __launch_bounds__(256) void k_final(
    const unsigned short* __restrict__ x3, const float* __restrict__ w,
    const float* __restrict__ b, float* __restrict__ outp, int n) {
    int wid  = (int)((blockIdx.x * (size_t)blockDim.x + threadIdx.x) >> 6);
    int lane = threadIdx.x & 63;
    if (wid >= n) return;
    float xv = fmaxf(bflo((unsigned)x3[(size_t)wid * 64 + lane]), 0.f);
    float acc = b[lane];
#pragma unroll
    for (int c = 0; c < 64; ++c) {
        float xc = __shfl(xv, c);
        acc += xc * w[c * 64 + lane];
    }
    float m = acc;
    for (int off = 1; off < 64; off <<= 1) m = fmaxf(m, __shfl_xor(m, off));
    float e = __expf(acc - m);
    float ssum = e;
    for (int off = 1; off < 64; off <<= 1) ssum += __shfl_xor(ssum, off);
    outp[(size_t)wid * 64 + lane] = acc - m - __logf(ssum);
}

// ---------------------------------------------------------------------------
extern "C" void kernel_launch(void* const* d_in, const int* in_sizes, int n_in,
                              void* d_out, int out_size, void* d_ws, size_t ws_size,
                              hipStream_t stream) {
    const float* x  = (const float*)d_in[0];
    const int*   ei = (const int*)d_in[1];
    const float* w1 = (const float*)d_in[2];
    const float* b1 = (const float*)d_in[3];
    const float* wq = (const float*)d_in[4];
    const float* bq = (const float*)d_in[5];
    const float* wk = (const float*)d_in[6];
    const float* bk = (const float*)d_in[7];
    const float* wv = (const float*)d_in[8];
    const float* bv = (const float*)d_in[9];
    const float* w2 = (const float*)d_in[10];
    const float* b2 = (const float*)d_in[11];
    float* outp = (float*)d_out;

    int n = in_sizes[0] / 256;
    int E = in_sizes[1] / 2;

    float* ws = (float*)d_ws;
    size_t off = 0;
    float* dinv = ws + off; off += (size_t)n;
    float* q    = ws + off; off += (size_t)n * 64;
    unsigned short* xsU = (unsigned short*)(ws + off); off += (size_t)n * 128;  // (L+1)*n*64 bf16
    unsigned short* kvU = (unsigned short*)(ws + off); off += (size_t)n * 192;  // n*384 bf16
    int* wsI    = (int*)(ws + off);
    int* counts = wsI;                 // n
    int* fill   = wsI + n;             // n
    int* startA = wsI + 2 * n;         // n+1
    int* ebuf   = wsI + 3 * n + 1;     // E

    // CSR build (counts+fill zeroed in one memset)
    hipMemsetAsync(counts, 0, 2 * (size_t)n * sizeof(int), stream);
    k_count<<<(E + 255) / 256, 256, 0, stream>>>(ei + E, counts, E);
    k_scan<<<1, 1024, 0, stream>>>(counts, startA, dinv, n);
    k_scatter<<<(E + 255) / 256, 256, 0, stream>>>(ei, startA, fill, ebuf, E);

    k_lin1<<<(n + 63) / 64, 256, 0, stream>>>(x, w1, b1, xsU, n);

    int attn_grid = (int)(((size_t)n * 64 + 255) / 256);
    for (int l = 0; l < NUM_LAYERS; ++l) {
        int t = l + 1;
        // layer 0: only V needed (softmax over 1 element == 1)
        int job_offset = (l == 0) ? 2 : 0;
        int njobs      = (l == 0) ? 1 : 1 + 2 * t;
        int kv_stride  = (t == 1) ? 64 : t * 128;
        dim3 grid((n + 63) / 64, njobs);
        k_qkv<<<grid, 256, 0, stream>>>(xsU, wq, bq, wk, bk, wv, bv,
                                        q, kvU, n, l, t, job_offset, kv_stride);
        unsigned short* dst = xsU + (size_t)(l + 1) * n * 64;
        if (t == 1)
            k_attn_g<1><<<attn_grid, 256, 0, stream>>>(startA, ebuf, dinv, q, kvU, dst, n);
        else if (t == 2)
            k_attn_g<2><<<attn_grid, 256, 0, stream>>>(startA, ebuf, dinv, q, kvU, dst, n);
        else
            k_attn_g<3><<<attn_grid, 256, 0, stream>>>(startA, ebuf, dinv, q, kvU, dst, n);
    }

    k_final<<<((int)(((long long)n * 64 + 255) / 256)), 256, 0, stream>>>(
        xsU + (size_t)NUM_LAYERS * n * 64, w2, b2, outp, n);
}

// Round 7
// 263.477 us; speedup vs baseline: 2.5952x; 1.0145x over previous
//
#include <hip/hip_runtime.h>
#include <math.h>

#define HID 64
#define HEADS 8
#define NUM_LAYERS 3

typedef __attribute__((ext_vector_type(8))) short bf16x8;
typedef __attribute__((ext_vector_type(4))) float f32x4;

// ---------------------------------------------------------------------------
// bf16 helpers (storage compression; accumulation stays f32)
// ---------------------------------------------------------------------------
__device__ __forceinline__ unsigned short f2bf(float f) {
    union { float f; unsigned int u; } cv; cv.f = f;
    unsigned int u = cv.u;
    unsigned int r = (u + 0x7FFFu + ((u >> 16) & 1u)) >> 16;  // RNE
    return (unsigned short)r;
}
__device__ __forceinline__ float bflo(unsigned int u) {
    union { unsigned int u; float f; } cv; cv.u = u << 16; return cv.f;
}
__device__ __forceinline__ float bfhi(unsigned int u) {
    union { unsigned int u; float f; } cv; cv.u = u & 0xFFFF0000u; return cv.f;
}
__device__ __forceinline__ unsigned relu_pk(unsigned u) {  // relu on 2 packed bf16
    unsigned m = ((u & 0x8000u) ? 0u : 0xFFFFu) |
                 ((u & 0x80000000u) ? 0u : 0xFFFF0000u);
    return u & m;
}

// ---------------------------------------------------------------------------
// CSR build: counts (atomic), fast single-block scan (+dinv), scatter
// ---------------------------------------------------------------------------
__global__ void k_count(const int* __restrict__ col, int* __restrict__ counts, int E) {
    int e = blockIdx.x * blockDim.x + threadIdx.x;
    if (e < E) atomicAdd(&counts[col[e]], 1);
}

// Single block, 1024 threads; each thread owns a contiguous chunk of
// ipt = ceil(n/1024) elements.  Serial chunk reduce -> block scan of 1024
// partials -> serial prefix write.  One pass instead of 20 serial rounds.
__global__ __launch_bounds__(1024) void k_scan(const int* __restrict__ counts,
                                               int* __restrict__ start,
                                               float* __restrict__ dinv, int n) {
    __shared__ int wsum[16];
    int tid = threadIdx.x;
    int lane = tid & 63, wv = tid >> 6;
    int ipt = (n + 1023) >> 10;
    int c0 = tid * ipt;
    int c1 = min(n, c0 + ipt);
    int s = 0;
    for (int i = c0; i < c1; ++i) s += counts[i];
    // wave inclusive scan
    int x = s;
#pragma unroll
    for (int off = 1; off < 64; off <<= 1) {
        int y = __shfl_up(x, off);
        if (lane >= off) x += y;
    }
    if (lane == 63) wsum[wv] = x;
    __syncthreads();
    if (wv == 0 && lane < 16) {
        int t2 = wsum[lane];
#pragma unroll
        for (int off = 1; off < 16; off <<= 1) {
            int y = __shfl_up(t2, off);
            if (lane >= off) t2 += y;
        }
        wsum[lane] = t2;
    }
    __syncthreads();
    int waveoff = (wv > 0) ? wsum[wv - 1] : 0;
    int run = waveoff + x - s;  // exclusive prefix at c0
    for (int i = c0; i < c1; ++i) {
        int v = counts[i];
        start[i] = run;
        dinv[i] = rsqrtf((float)(v + 1));  // +1 self-loop
        run += v;
    }
    if (tid == 0) start[n] = wsum[15];
}

__global__ void k_scatter(const int* __restrict__ ei, const int* __restrict__ start,
                          int* __restrict__ fill, int* __restrict__ ebuf, int E) {
    int e = blockIdx.x * blockDim.x + threadIdx.x;
    if (e >= E) return;
    int r = ei[e], c = ei[E + e];
    int pos = start[c] + atomicAdd(&fill[c], 1);
    ebuf[pos] = r;
}

// ---------------------------------------------------------------------------
// MFMA GEMM core: block = 64 nodes x 64 oc, 4 waves, wave w = 16-row strip.
// A in LDS row-major bf16 (stride 72); W in LDS transposed bf16 [n][k].
// A-frag: A[m=lane&15][k=quad*8+j]; C/D: col=lane&15, row=quad*4+reg.
// ---------------------------------------------------------------------------
#define ALD 72

__device__ __forceinline__ void stage_w_bf16(unsigned short* Wt,
                                             const float* __restrict__ w, int tid) {
    for (int idx = tid; idx < 1024; idx += 256) {
        int k = idx >> 4, n4 = (idx & 15) * 4;
        float4 wv = *(const float4*)&w[k * 64 + n4];
        Wt[(n4 + 0) * ALD + k] = f2bf(wv.x);
        Wt[(n4 + 1) * ALD + k] = f2bf(wv.y);
        Wt[(n4 + 2) * ALD + k] = f2bf(wv.z);
        Wt[(n4 + 3) * ALD + k] = f2bf(wv.w);
    }
}

__device__ __forceinline__ void mfma_step(const unsigned short* Alds,
                                          const unsigned short* Wt,
                                          int tid, f32x4 acc[4]) {
    int lane = tid & 63;
    int m0 = (tid >> 6) * 16;
    int c16 = lane & 15, quad = lane >> 4;
    const unsigned short* ar = &Alds[(m0 + c16) * ALD + quad * 8];
    bf16x8 a0 = *(const bf16x8*)ar;
    bf16x8 a1 = *(const bf16x8*)(ar + 32);
#pragma unroll
    for (int nt = 0; nt < 4; ++nt) {
        const unsigned short* br = &Wt[(nt * 16 + c16) * ALD + quad * 8];
        bf16x8 b0 = *(const bf16x8*)br;
        bf16x8 b1 = *(const bf16x8*)(br + 32);
        acc[nt] = __builtin_amdgcn_mfma_f32_16x16x32_bf16(a0, b0, acc[nt], 0, 0, 0);
        acc[nt] = __builtin_amdgcn_mfma_f32_16x16x32_bf16(a1, b1, acc[nt], 0, 0, 0);
    }
}

// ---------------------------------------------------------------------------
// lin1 (+ fused layer-0 V GEMM):
//   h  = relu(x @ W1 + b1)            -> bf16 global (xs slice 0)
//   V0 = h @ Wv[0] + bv[0]            -> bf16 kv (stride 64, offset 0)
// h tile round-trips through LDS for the second MFMA pass.
// ---------------------------------------------------------------------------
__global__ __launch_bounds__(256, 4) void k_lin1(
    const float* __restrict__ x, const float* __restrict__ w,
    const float* __restrict__ b, const float* __restrict__ wv0,
    const float* __restrict__ bv0, unsigned short* __restrict__ h,
    unsigned short* __restrict__ kv, int n) {
    __shared__ __align__(16) unsigned short Alds[64 * ALD];
    __shared__ __align__(16) unsigned short Wt[64 * ALD];
    int tid = threadIdx.x;
    int node0 = blockIdx.x * 64;
    f32x4 acc[4];
#pragma unroll
    for (int nt = 0; nt < 4; ++nt) acc[nt] = (f32x4){0.f, 0.f, 0.f, 0.f};

    for (int kc = 0; kc < 256; kc += 64) {
        __syncthreads();
        stage_w_bf16(Wt, w + kc * 64, tid);
        for (int idx = tid; idx < 1024; idx += 256) {
            int r = idx >> 4, c4 = (idx & 15) * 4;
            int node = node0 + r;
            float4 v = make_float4(0.f, 0.f, 0.f, 0.f);
            if (node < n) v = *(const float4*)&x[(size_t)node * 256 + kc + c4];
            Alds[r * ALD + c4 + 0] = f2bf(v.x);
            Alds[r * ALD + c4 + 1] = f2bf(v.y);
            Alds[r * ALD + c4 + 2] = f2bf(v.z);
            Alds[r * ALD + c4 + 3] = f2bf(v.w);
        }
        __syncthreads();
        mfma_step(Alds, Wt, tid, acc);
    }
    int lane = tid & 63;
    int m0 = (tid >> 6) * 16, c16 = lane & 15, quad = lane >> 4;
    float bias[4];
#pragma unroll
    for (int nt = 0; nt < 4; ++nt) bias[nt] = b[nt * 16 + c16];

    __syncthreads();  // all waves done reading LDS from last chunk
    stage_w_bf16(Wt, wv0, tid);
#pragma unroll
    for (int i = 0; i < 4; ++i) {
        int row = m0 + quad * 4 + i;
        int node = node0 + row;
#pragma unroll
        for (int nt = 0; nt < 4; ++nt) {
            unsigned short hb = f2bf(fmaxf(acc[nt][i] + bias[nt], 0.f));
            Alds[row * ALD + nt * 16 + c16] = hb;
            if (node < n) h[(size_t)node * 64 + nt * 16 + c16] = hb;
        }
    }
    __syncthreads();
    f32x4 acc2[4];
#pragma unroll
    for (int nt = 0; nt < 4; ++nt) acc2[nt] = (f32x4){0.f, 0.f, 0.f, 0.f};
    mfma_step(Alds, Wt, tid, acc2);
    float bias2[4];
#pragma unroll
    for (int nt = 0; nt < 4; ++nt) bias2[nt] = bv0[nt * 16 + c16];
#pragma unroll
    for (int i = 0; i < 4; ++i) {
        int node = node0 + m0 + quad * 4 + i;
        if (node < n) {
#pragma unroll
            for (int nt = 0; nt < 4; ++nt)
                kv[(size_t)node * 64 + nt * 16 + c16] = f2bf(acc2[nt][i] + bias2[nt]);
        }
    }
}

// ---------------------------------------------------------------------------
// batched 64x64 MFMA GEMM for q / K / V of one layer (layers 1..2).
// job: 0 -> q (f32), 1..t -> K slice s, t+1..2t -> V slice s (bf16 kv).
// kv layout [node][s][K64|V64], stride t*128.
// ---------------------------------------------------------------------------
__global__ __launch_bounds__(256, 4) void k_qkv(
    const unsigned short* __restrict__ xsbase,
    const float* __restrict__ wq, const float* __restrict__ bq,
    const float* __restrict__ wk, const float* __restrict__ bk,
    const float* __restrict__ wv, const float* __restrict__ bv,
    float* __restrict__ q, unsigned short* __restrict__ kv,
    int n, int layer, int t, int kv_stride) {
    int job = blockIdx.y;
    const unsigned short* src; const float* w; const float* b; bool relu_in;
    int kv_off = 0;
    if (job == 0) {
        src = xsbase + (size_t)layer * n * 64;
        w = wq + layer * 4096; b = bq + layer * 64;
        relu_in = (layer >= 1);
    } else if (job <= t) {
        int s = job - 1;
        src = xsbase + (size_t)s * n * 64;
        w = wk + layer * 4096; b = bk + layer * 64;
        kv_off = s * 128;
        relu_in = (s >= 1);
    } else {
        int s = job - t - 1;
        src = xsbase + (size_t)s * n * 64;
        w = wv + layer * 4096; b = bv + layer * 64;
        kv_off = s * 128 + 64;
        relu_in = (s >= 1);
    }
    __shared__ __align__(16) unsigned short Alds[64 * ALD];
    __shared__ __align__(16) unsigned short Wt[64 * ALD];
    int tid = threadIdx.x;
    int node0 = blockIdx.x * 64;
    stage_w_bf16(Wt, w, tid);
    for (int idx = tid; idx < 512; idx += 256) {
        int r = idx >> 3, seg = idx & 7;
        int node = node0 + r;
        uint4 u = make_uint4(0u, 0u, 0u, 0u);
        if (node < n) u = *(const uint4*)&src[(size_t)node * 64 + seg * 8];
        if (relu_in) {
            u.x = relu_pk(u.x); u.y = relu_pk(u.y);
            u.z = relu_pk(u.z); u.w = relu_pk(u.w);
        }
        *(uint4*)&Alds[r * ALD + seg * 8] = u;
    }
    __syncthreads();
    f32x4 acc[4];
#pragma unroll
    for (int nt = 0; nt < 4; ++nt) acc[nt] = (f32x4){0.f, 0.f, 0.f, 0.f};
    mfma_step(Alds, Wt, tid, acc);

    int lane = tid & 63;
    int m0 = (tid >> 6) * 16, c16 = lane & 15, quad = lane >> 4;
    float bias[4];
#pragma unroll
    for (int nt = 0; nt < 4; ++nt) bias[nt] = b[nt * 16 + c16];
    if (job == 0) {
#pragma unroll
        for (int i = 0; i < 4; ++i) {
            int node = node0 + m0 + quad * 4 + i;
            if (node < n) {
#pragma unroll
                for (int nt = 0; nt < 4; ++nt)
                    q[(size_t)node * 64 + nt * 16 + c16] = acc[nt][i] + bias[nt];
            }
        }
    } else {
#pragma unroll
        for (int i = 0; i < 4; ++i) {
            int node = node0 + m0 + quad * 4 + i;
            if (node < n) {
#pragma unroll
                for (int nt = 0; nt < 4; ++nt)
                    kv[(size_t)node * kv_stride + kv_off + nt * 16 + c16] =
                        f2bf(acc[nt][i] + bias[nt]);
            }
        }
    }
}

// ---------------------------------------------------------------------------
// attention + aggregate, CSR by destination.  One wave per node.
// Lane = (edge-slot g = lane>>3, head h = lane&7): 8 edges in flight,
// lane-local dot/softmax.  T==1: pure dinv-weighted V gather (kv stride 64).
// Outputs bf16 xs slice.
// ---------------------------------------------------------------------------
template <int T>
__global__ __launch_bounds__(256) void k_attn_g(
    const int* __restrict__ start, const int* __restrict__ ebuf,
    const float* __restrict__ dinv, const float* __restrict__ q,
    const unsigned short* __restrict__ kv, unsigned short* __restrict__ outp, int n) {
    const int KVS = (T == 1) ? 64 : T * 128;
    int node = (int)((blockIdx.x * (size_t)blockDim.x + threadIdx.x) >> 6);
    int lane = threadIdx.x & 63;
    if (node >= n) return;
    int g = lane >> 3;
    int cb = (lane & 7) * 8;
    const float isd = 0.35355339059327373f;  // 1/sqrt(8)

    float qv[8];
    if (T > 1) {
        float4 q0 = *(const float4*)&q[(size_t)node * 64 + cb];
        float4 q1 = *(const float4*)&q[(size_t)node * 64 + cb + 4];
        qv[0] = q0.x; qv[1] = q0.y; qv[2] = q0.z; qv[3] = q0.w;
        qv[4] = q1.x; qv[5] = q1.y; qv[6] = q1.z; qv[7] = q1.w;
    }
    float dc = dinv[node];
    int s0 = start[node];
    int cnt = start[node + 1] - s0 + 1;

    float acc[8];
#pragma unroll
    for (int k = 0; k < 8; ++k) acc[k] = 0.f;

    for (int base = 0; base < cnt; base += 8) {
        int idx = base + g;
        bool valid = idx < cnt;
        int r = node;
        if (valid && idx > 0) r = ebuf[s0 + idx - 1];
        float dr = valid ? dinv[r] : 0.f;
        const unsigned short* rkv = kv + (size_t)r * KVS;

        float sc[T];
        float wgt;
        if (T > 1) {
            float m = -1e30f;
#pragma unroll
            for (int s = 0; s < T; ++s) {
                uint4 ku = *(const uint4*)&rkv[s * 128 + cb];
                float p = qv[0] * bflo(ku.x) + qv[1] * bfhi(ku.x)
                        + qv[2] * bflo(ku.y) + qv[3] * bfhi(ku.y)
                        + qv[4] * bflo(ku.z) + qv[5] * bfhi(ku.z)
                        + qv[6] * bflo(ku.w) + qv[7] * bfhi(ku.w);
                p *= isd;
                sc[s] = p;
                m = fmaxf(m, p);
            }
            float denom = 0.f;
#pragma unroll
            for (int s = 0; s < T; ++s) { sc[s] = __expf(sc[s] - m); denom += sc[s]; }
            wgt = dr / denom;
        } else {
            sc[0] = 1.f;
            wgt = dr;
        }

        float mg[8];
#pragma unroll
        for (int k = 0; k < 8; ++k) mg[k] = 0.f;
#pragma unroll
        for (int s = 0; s < T; ++s) {
            uint4 vu = *(const uint4*)&rkv[((T == 1) ? 0 : s * 128 + 64) + cb];
            float wv_ = sc[s];
            mg[0] += wv_ * bflo(vu.x); mg[1] += wv_ * bfhi(vu.x);
            mg[2] += wv_ * bflo(vu.y); mg[3] += wv_ * bfhi(vu.y);
            mg[4] += wv_ * bflo(vu.z); mg[5] += wv_ * bfhi(vu.z);
            mg[6] += wv_ * bflo(vu.w); mg[7] += wv_ * bfhi(vu.w);
        }
#pragma unroll
        for (int k = 0; k < 8; ++k) acc[k] += wgt * mg[k];
    }

#pragma unroll
    for (int off = 8; off < 64; off <<= 1) {
#pragma unroll
        for (int k = 0; k < 8; ++k) acc[k] += __shfl_xor(acc[k], off);
    }
    if (g == 0) {
        ushort4 o0, o1;
        o0.x = f2bf(acc[0] * dc); o0.y = f2bf(acc[1] * dc);
        o0.z = f2bf(acc[2] * dc); o0.w = f2bf(acc[3] * dc);
        o1.x = f2bf(acc[4] * dc); o1.y = f2bf(acc[5] * dc);
        o1.z = f2bf(acc[6] * dc); o1.w = f2bf(acc[7] * dc);
        *(ushort4*)&outp[(size_t)node * 64 + cb] = o0;
        *(ushort4*)&outp[(size_t)node * 64 + cb + 4] = o1;
    }
}

// ---------------------------------------------------------------------------
// layer-2 attention fused with final projection + log_softmax.
// Same structure as k_attn_g<3>, but after the butterfly every lane holds the
// full x3 row; shfl-broadcast into logits = relu(x3)@W2 + b2 -> log_softmax.
// ---------------------------------------------------------------------------
__global__ __launch_bounds__(256) void k_attn3f(
    const int* __restrict__ start, const int* __restrict__ ebuf,
    const float* __restrict__ dinv, const float* __restrict__ q,
    const unsigned short* __restrict__ kv,
    const float* __restrict__ w2, const float* __restrict__ b2,
    float* __restrict__ outp, int n) {
    const int T = 3, KVS = 384;
    int node = (int)((blockIdx.x * (size_t)blockDim.x + threadIdx.x) >> 6);
    int lane = threadIdx.x & 63;
    if (node >= n) return;
    int g = lane >> 3;
    int cb = (lane & 7) * 8;
    const float isd = 0.35355339059327373f;

    float qv[8];
    {
        float4 q0 = *(const float4*)&q[(size_t)node * 64 + cb];
        float4 q1 = *(const float4*)&q[(size_t)node * 64 + cb + 4];
        qv[0] = q0.x; qv[1] = q0.y; qv[2] = q0.z; qv[3] = q0.w;
        qv[4] = q1.x; qv[5] = q1.y; qv[6] = q1.z; qv[7] = q1.w;
    }
    float dc = dinv[node];
    int s0 = start[node];
    int cnt = start[node + 1] - s0 + 1;

    float acc[8];
#pragma unroll
    for (int k = 0; k < 8; ++k) acc[k] = 0.f;

    for (int base = 0; base < cnt; base += 8) {
        int idx = base + g;
        bool valid = idx < cnt;
        int r = node;
        if (valid && idx > 0) r = ebuf[s0 + idx - 1];
        float dr = valid ? dinv[r] : 0.f;
        const unsigned short* rkv = kv + (size_t)r * KVS;

        float sc[T];
        float m = -1e30f;
#pragma unroll
        for (int s = 0; s < T; ++s) {
            uint4 ku = *(const uint4*)&rkv[s * 128 + cb];
            float p = qv[0] * bflo(ku.x) + qv[1] * bfhi(ku.x)
                    + qv[2] * bflo(ku.y) + qv[3] * bfhi(ku.y)
                    + qv[4] * bflo(ku.z) + qv[5] * bfhi(ku.z)
                    + qv[6] * bflo(ku.w) + qv[7] * bfhi(ku.w);
            p *= isd;
            sc[s] = p;
            m = fmaxf(m, p);
        }
        float denom = 0.f;
#pragma unroll
        for (int s = 0; s < T; ++s) { sc[s] = __expf(sc[s] - m); denom += sc[s]; }
        float wgt = dr / denom;

        float mg[8];
#pragma unroll
        for (int k = 0; k < 8; ++k) mg[k] = 0.f;
#pragma unroll
        for (int s = 0; s < T; ++s) {
            uint4 vu = *(const uint4*)&rkv[s * 128 + 64 + cb];
            float wv_ = sc[s];
            mg[0] += wv_ * bflo(vu.x); mg[1] += wv_ * bfhi(vu.x);
            mg[2] += wv_ * bflo(vu.y); mg[3] += wv_ * bfhi(vu.y);
            mg[4] += wv_ * bflo(vu.z); mg[5] += wv_ * bfhi(vu.z);
            mg[6] += wv_ * bflo(vu.w); mg[7] += wv_ * bfhi(vu.w);
        }
#pragma unroll
        for (int k = 0; k < 8; ++k) acc[k] += wgt * mg[k];
    }

#pragma unroll
    for (int off = 8; off < 64; off <<= 1) {
#pragma unroll
        for (int k = 0; k < 8; ++k) acc[k] += __shfl_xor(acc[k], off);
    }
    // every lane now holds the full x3 row: channel c lives in lane (c>>3)
    // (g=0 group), register acc[c&7].  Fused final projection:
    float lg = b2[lane];
#pragma unroll
    for (int c = 0; c < 64; ++c) {
        float xc = fmaxf(__shfl(acc[c & 7], c >> 3) * dc, 0.f);
        lg += xc * w2[c * 64 + lane];
    }
    float mx = lg;
#pragma unroll
    for (int off = 1; off < 64; off <<= 1) mx = fmaxf(mx, __shfl_xor(mx, off));
    float e = __expf(lg - mx);
    float ssum = e;
#pragma unroll
    for (int off = 1; off < 64; off <<= 1) ssum += __shfl_xor(ssum, off);
    outp[(size_t)node * 64 + lane] = lg - mx - __logf(ssum);
}

// ---------------------------------------------------------------------------
extern "C" void kernel_launch(void* const* d_in, const int* in_sizes, int n_in,
                              void* d_out, int out_size, void* d_ws, size_t ws_size,
                              hipStream_t stream) {
    const float* x  = (const float*)d_in[0];
    const int*   ei = (const int*)d_in[1];
    const float* w1 = (const float*)d_in[2];
    const float* b1 = (const float*)d_in[3];
    const float* wq = (const float*)d_in[4];
    const float* bq = (const float*)d_in[5];
    const float* wk = (const float*)d_in[6];
    const float* bk = (const float*)d_in[7];
    const float* wv = (const float*)d_in[8];
    const float* bv = (const float*)d_in[9];
    const float* w2 = (const float*)d_in[10];
    const float* b2 = (const float*)d_in[11];
    float* outp = (float*)d_out;

    int n = in_sizes[0] / 256;
    int E = in_sizes[1] / 2;

    float* ws = (float*)d_ws;
    size_t off = 0;
    float* dinv = ws + off; off += (size_t)n;
    float* q    = ws + off; off += (size_t)n * 64;
    unsigned short* xsU = (unsigned short*)(ws + off); off += (size_t)n * 96;   // 3 slices bf16
    unsigned short* kvU = (unsigned short*)(ws + off); off += (size_t)n * 192;  // n*384 bf16
    int* wsI    = (int*)(ws + off);
    int* counts = wsI;                 // n
    int* fill   = wsI + n;             // n
    int* startA = wsI + 2 * n;         // n+1
    int* ebuf   = wsI + 3 * n + 1;     // E

    // CSR build
    hipMemsetAsync(counts, 0, 2 * (size_t)n * sizeof(int), stream);
    k_count<<<(E + 255) / 256, 256, 0, stream>>>(ei + E, counts, E);
    k_scan<<<1, 1024, 0, stream>>>(counts, startA, dinv, n);
    k_scatter<<<(E + 255) / 256, 256, 0, stream>>>(ei, startA, fill, ebuf, E);

    // lin1 + fused layer-0 V GEMM (kv stride 64)
    k_lin1<<<(n + 63) / 64, 256, 0, stream>>>(x, w1, b1, wv, bv, xsU, kvU, n);

    int attn_grid = (int)(((size_t)n * 64 + 255) / 256);

    // layer 0 attention (T=1)
    k_attn_g<1><<<attn_grid, 256, 0, stream>>>(startA, ebuf, dinv, q, kvU,
                                               xsU + (size_t)n * 64, n);
    // layer 1
    {
        dim3 grid((n + 63) / 64, 5);
        k_qkv<<<grid, 256, 0, stream>>>(xsU, wq, bq, wk, bk, wv, bv,
                                        q, kvU, n, 1, 2, 256);
        k_attn_g<2><<<attn_grid, 256, 0, stream>>>(startA, ebuf, dinv, q, kvU,
                                                   xsU + (size_t)n * 128, n);
    }
    // layer 2 + fused final
    {
        dim3 grid((n + 63) / 64, 7);
        k_qkv<<<grid, 256, 0, stream>>>(xsU, wq, bq, wk, bk, wv, bv,
                                        q, kvU, n, 2, 3, 384);
        k_attn3f<<<attn_grid, 256, 0, stream>>>(startA, ebuf, dinv, q, kvU,
                                                w2, b2, outp, n);
    }
}